// Round 1
// baseline (1677.807 us; speedup 1.0000x reference)
//
#include <hip/hip_runtime.h>
#include <cmath>

#define NN 10000
#define NE 160000
#define INV_SQRT_C 0.08838834764831845f   // 1/sqrt(128)
#define INV_SQRT3F 0.5773502691896258f

typedef _Float16 f16x8 __attribute__((ext_vector_type(8)));
typedef float    f32x4 __attribute__((ext_vector_type(4)));

__device__ __forceinline__ float silu_f(float x) {
  return x / (1.f + __expf(-x));
}

// ---------------------------------------------------------------------------
// Weight conversion fp32 -> fp16, swizzled for MFMA B-fragments:
//   dst[(kb*N + n)*32 + kk] = src[k*N + n] * scale,  k = kb*32 + kk (0 if k>=Korig)
// so a lane (n = lane&15 + tile base, k-chunk g*8..g*8+7) reads 16B contiguous.
// ---------------------------------------------------------------------------
__global__ void wconv(const float* __restrict__ src, _Float16* __restrict__ dst,
                      int Korig, int Kpad, int N, float scale) {
  int total = Kpad * N;
  for (int t = blockIdx.x * blockDim.x + threadIdx.x; t < total;
       t += gridDim.x * blockDim.x) {
    int n = t % N;
    int k = t / N;
    int kb = k >> 5, kk = k & 31;
    float v = (k < Korig) ? src[(size_t)k * N + n] * scale : 0.f;
    dst[((size_t)(kb * N + n) << 5) + kk] = (_Float16)v;
  }
}

// ---------------------------------------------------------------------------
// Node pre-pass: per node n (s = feats[0:128], v[i][c] = feats[128+i*3+c]):
//  y=0: up_s  -> UP[n*512 + j]
//  y=1: up_v  -> UP[n*512 + 128 + j*3 + c]
//  y=2: sc_s  -> out_sc[n*512 + j]
//  y=3: sc_v  -> out_sc[n*512 + 128 + j*3 + c]
//  y=4: down  -> DOWNH[n*64 + j]  (fp16)
// all scaled by 1/sqrt(128). 16 nodes per block, 256 threads.
// ---------------------------------------------------------------------------
__global__ __launch_bounds__(256) void node_pre(
    const float* __restrict__ feats,
    const float* __restrict__ W_up0, const float* __restrict__ W_up1,
    const float* __restrict__ W_skip0, const float* __restrict__ W_skip1,
    const float* __restrict__ W_down,
    float* __restrict__ UP, _Float16* __restrict__ DOWNH,
    float* __restrict__ out_sc) {
  __shared__ float ls[16 * 384];
  const int y = blockIdx.y;
  const int n0 = blockIdx.x * 16;
  const int t = threadIdx.x;

  if (y == 0 || y == 2 || y == 4) {
    for (int f = t; f < 16 * 128; f += 256) {
      int r = f >> 7, c = f & 127;
      ls[r * 128 + c] = feats[(size_t)(n0 + r) * 512 + c];
    }
    __syncthreads();
    if (y == 4) {
      int j = t & 63, g = t >> 6;  // 4 nodes per group
      float acc[4] = {0.f, 0.f, 0.f, 0.f};
      for (int i = 0; i < 128; ++i) {
        float w = W_down[(size_t)i * 64 + j];
#pragma unroll
        for (int r = 0; r < 4; ++r) acc[r] += ls[(g * 4 + r) * 128 + i] * w;
      }
#pragma unroll
      for (int r = 0; r < 4; ++r)
        DOWNH[(size_t)(n0 + g * 4 + r) * 64 + j] = (_Float16)(acc[r] * INV_SQRT_C);
    } else {
      const float* W = (y == 0) ? W_up0 : W_skip0;
      int j = t & 127, g = t >> 7;  // 8 nodes per group
      float acc[8] = {0.f, 0.f, 0.f, 0.f, 0.f, 0.f, 0.f, 0.f};
      for (int i = 0; i < 128; ++i) {
        float w = W[(size_t)i * 128 + j];
#pragma unroll
        for (int r = 0; r < 8; ++r) acc[r] += ls[(g * 8 + r) * 128 + i] * w;
      }
#pragma unroll
      for (int r = 0; r < 8; ++r) {
        int n = n0 + g * 8 + r;
        float v = acc[r] * INV_SQRT_C;
        if (y == 0) UP[(size_t)n * 512 + j] = v;
        else        out_sc[(size_t)n * 512 + j] = v;
      }
    }
  } else {
    for (int f = t; f < 16 * 384; f += 256) {
      int r = f / 384, c = f % 384;
      ls[r * 384 + c] = feats[(size_t)(n0 + r) * 512 + 128 + c];
    }
    __syncthreads();
    const float* W = (y == 1) ? W_up1 : W_skip1;
    int j = t & 127, g = t >> 7;
    float acc[8][3];
#pragma unroll
    for (int r = 0; r < 8; ++r)
#pragma unroll
      for (int c = 0; c < 3; ++c) acc[r][c] = 0.f;
    for (int i = 0; i < 128; ++i) {
      float w = W[(size_t)i * 128 + j];
#pragma unroll
      for (int r = 0; r < 8; ++r) {
#pragma unroll
        for (int c = 0; c < 3; ++c)
          acc[r][c] += ls[(g * 8 + r) * 384 + i * 3 + c] * w;
      }
    }
#pragma unroll
    for (int r = 0; r < 8; ++r) {
      int n = n0 + g * 8 + r;
#pragma unroll
      for (int c = 0; c < 3; ++c) {
        float v = acc[r][c] * INV_SQRT_C;
        if (y == 1) UP[(size_t)n * 512 + 128 + j * 3 + c] = v;
        else        out_sc[(size_t)n * 512 + 128 + j * 3 + c] = v;
      }
    }
  }
}

// ---------------------------------------------------------------------------
// Fused edge kernel: 4-layer MLP (fp16 MFMA 16x16x32) + tensor product +
// atomic scatter. 64 edges per block, 256 threads (4 waves, each owns 64 cols).
// h tiles ping-pong between two 64x256 fp16 LDS buffers; addressing is
// XOR-swizzled in 16-col blocks to avoid LD=256 bank conflicts:
//   idx(row,col) = row*256 + (((col>>4) ^ (row&15))<<4) + (col&15)
// ---------------------------------------------------------------------------
__device__ __forceinline__ void mlp_layer_256(
    const _Float16* In, _Float16* Out, const _Float16* __restrict__ Wz,
    int m, int g, int wv) {
  f32x4 acc[4][4];
  f32x4 zero4 = {0.f, 0.f, 0.f, 0.f};
#pragma unroll
  for (int rt = 0; rt < 4; ++rt)
#pragma unroll
    for (int ct = 0; ct < 4; ++ct) acc[rt][ct] = zero4;

#pragma unroll
  for (int kb = 0; kb < 8; ++kb) {
    f16x8 a[4], b[4];
#pragma unroll
    for (int rt = 0; rt < 4; ++rt) {
      int row = rt * 16 + m;
      a[rt] = *(const f16x8*)&In[row * 256 + (((kb * 2 + (g >> 1)) ^ m) << 4) + (g & 1) * 8];
    }
#pragma unroll
    for (int ct = 0; ct < 4; ++ct)
      b[ct] = *(const f16x8*)&Wz[((size_t)(kb * 256 + wv * 64 + ct * 16 + m) << 5) + g * 8];
#pragma unroll
    for (int rt = 0; rt < 4; ++rt)
#pragma unroll
      for (int ct = 0; ct < 4; ++ct)
        acc[rt][ct] = __builtin_amdgcn_mfma_f32_16x16x32_f16(a[rt], b[ct], acc[rt][ct], 0, 0, 0);
  }
  // silu -> Out (C/D layout: col = lane&15, row = quad*4 + reg)
#pragma unroll
  for (int rt = 0; rt < 4; ++rt)
#pragma unroll
    for (int ct = 0; ct < 4; ++ct)
#pragma unroll
      for (int q = 0; q < 4; ++q) {
        int row = rt * 16 + g * 4 + q;
        float s = silu_f(acc[rt][ct][q]);
        Out[row * 256 + (((wv * 4 + ct) ^ (g * 4 + q)) << 4) + m] = (_Float16)s;
      }
}

__global__ __launch_bounds__(256, 2) void edge_mlp(
    const float* __restrict__ edge_attrs,
    const float* __restrict__ edge_feats,
    const int* __restrict__ edge_index,
    const _Float16* __restrict__ DOWNH,
    const float* __restrict__ UP,
    const _Float16* __restrict__ W0h, const _Float16* __restrict__ W1h,
    const _Float16* __restrict__ W2h, const _Float16* __restrict__ W3h,
    float* __restrict__ M0, float* __restrict__ M1) {
  __shared__ _Float16 HA[64 * 256];
  __shared__ _Float16 HB[64 * 256];

  const int tid = threadIdx.x;
  const int lane = tid & 63;
  const int wv = tid >> 6;
  const int m = lane & 15;
  const int g = lane >> 4;
  const int e0 = blockIdx.x * 64;
  const int nw = wv * 64;

  // per-lane sender/receiver for A-fragment rows (row index = m)
  int snd_r[4], rcv_r[4];
#pragma unroll
  for (int rt = 0; rt < 4; ++rt) {
    int2 sr = *(const int2*)&edge_index[(size_t)(e0 + rt * 16 + m) * 2];
    snd_r[rt] = sr.x;
    rcv_r[rt] = sr.y;
  }

  f32x4 zero4 = {0.f, 0.f, 0.f, 0.f};
  f16x8 zf = {0, 0, 0, 0, 0, 0, 0, 0};

  // ---------------- layer 0: aug(136, padded 160) -> h1 (HA)
  {
    f32x4 acc[4][4];
#pragma unroll
    for (int rt = 0; rt < 4; ++rt)
#pragma unroll
      for (int ct = 0; ct < 4; ++ct) acc[rt][ct] = zero4;

#pragma unroll
    for (int kb = 0; kb < 5; ++kb) {
      const int k0 = kb * 32 + g * 8;
      f16x8 a[4], b[4];
#pragma unroll
      for (int rt = 0; rt < 4; ++rt) {
        if (k0 == 0) {  // edge_feats chunk
          const float* ef = &edge_feats[(size_t)(e0 + rt * 16 + m) * 8];
          float4 f0 = *(const float4*)ef;
          float4 f1 = *(const float4*)(ef + 4);
          f16x8 av;
          av[0] = (_Float16)f0.x; av[1] = (_Float16)f0.y;
          av[2] = (_Float16)f0.z; av[3] = (_Float16)f0.w;
          av[4] = (_Float16)f1.x; av[5] = (_Float16)f1.y;
          av[6] = (_Float16)f1.z; av[7] = (_Float16)f1.w;
          a[rt] = av;
        } else if (k0 < 72) {  // down[sender] chunk
          a[rt] = *(const f16x8*)&DOWNH[(size_t)snd_r[rt] * 64 + (k0 - 8)];
        } else if (k0 < 136) {  // down[receiver] chunk
          a[rt] = *(const f16x8*)&DOWNH[(size_t)rcv_r[rt] * 64 + (k0 - 72)];
        } else {  // zero pad
          a[rt] = zf;
        }
      }
#pragma unroll
      for (int ct = 0; ct < 4; ++ct)
        b[ct] = *(const f16x8*)&W0h[((size_t)(kb * 256 + nw + ct * 16 + m) << 5) + g * 8];
#pragma unroll
      for (int rt = 0; rt < 4; ++rt)
#pragma unroll
        for (int ct = 0; ct < 4; ++ct)
          acc[rt][ct] = __builtin_amdgcn_mfma_f32_16x16x32_f16(a[rt], b[ct], acc[rt][ct], 0, 0, 0);
    }
#pragma unroll
    for (int rt = 0; rt < 4; ++rt)
#pragma unroll
      for (int ct = 0; ct < 4; ++ct)
#pragma unroll
        for (int q = 0; q < 4; ++q) {
          int row = rt * 16 + g * 4 + q;
          float s = silu_f(acc[rt][ct][q]);
          HA[row * 256 + (((wv * 4 + ct) ^ (g * 4 + q)) << 4) + m] = (_Float16)s;
        }
  }
  __syncthreads();

  mlp_layer_256(HA, HB, W1h, m, g, wv);   // layer 1: h1 -> h2
  __syncthreads();
  mlp_layer_256(HB, HA, W2h, m, g, wv);   // layer 2: h2 -> h3
  __syncthreads();

  // ---------------- layer 3: h3 -> tpw (512 cols, two halves) + TP + scatter
  for (int half = 0; half < 2; ++half) {
    f32x4 acc[4][4];
#pragma unroll
    for (int rt = 0; rt < 4; ++rt)
#pragma unroll
      for (int ct = 0; ct < 4; ++ct) acc[rt][ct] = zero4;

#pragma unroll
    for (int kb = 0; kb < 8; ++kb) {
      f16x8 a[4], b[4];
#pragma unroll
      for (int rt = 0; rt < 4; ++rt) {
        int row = rt * 16 + m;
        a[rt] = *(const f16x8*)&HA[row * 256 + (((kb * 2 + (g >> 1)) ^ m) << 4) + (g & 1) * 8];
      }
#pragma unroll
      for (int ct = 0; ct < 4; ++ct)
        b[ct] = *(const f16x8*)&W3h[((size_t)(kb * 512 + half * 256 + nw + ct * 16 + m) << 5) + g * 8];
#pragma unroll
      for (int rt = 0; rt < 4; ++rt)
#pragma unroll
        for (int ct = 0; ct < 4; ++ct)
          acc[rt][ct] = __builtin_amdgcn_mfma_f32_16x16x32_f16(a[rt], b[ct], acc[rt][ct], 0, 0, 0);
    }

    // epilogue: tpw element (edge el, channel col) -> tensor product -> atomics
#pragma unroll
    for (int rt = 0; rt < 4; ++rt) {
#pragma unroll
      for (int q = 0; q < 4; ++q) {
        int el = e0 + rt * 16 + g * 4 + q;
        int2 sr = *(const int2*)&edge_index[(size_t)el * 2];
        float4 ya = *(const float4*)&edge_attrs[(size_t)el * 4];
#pragma unroll
        for (int ct = 0; ct < 4; ++ct) {
          int col = half * 256 + nw + ct * 16 + m;
          float wval = acc[rt][ct][q];
          int sel = col >> 7;  // wave-uniform (col range per wave is 64-aligned)
          if (sel == 0) {          // w1: out0a = w1*xs*y0
            int i = col;
            float xs = UP[(size_t)sr.x * 512 + i];
            atomicAdd(&M0[(size_t)sr.y * 256 + i], wval * xs * ya.x);
          } else if (sel == 1) {   // w2: out1a = (w2*xs) x yv
            int i = col - 128;
            float t = wval * UP[(size_t)sr.x * 512 + i];
            float* base = &M1[(size_t)sr.y * 768 + i * 3];
            atomicAdd(base + 0, t * ya.y);
            atomicAdd(base + 1, t * ya.z);
            atomicAdd(base + 2, t * ya.w);
          } else if (sel == 2) {   // w3: out1b = w3*xv*y0
            int i = col - 256;
            const float* xv = &UP[(size_t)sr.x * 512 + 128 + i * 3];
            float t = wval * ya.x;
            float* base = &M1[(size_t)sr.y * 768 + (128 + i) * 3];
            atomicAdd(base + 0, t * xv[0]);
            atomicAdd(base + 1, t * xv[1]);
            atomicAdd(base + 2, t * xv[2]);
          } else {                 // w4: out0b = w4*dot(xv,yv)/sqrt(3)
            int i = col - 384;
            const float* xv = &UP[(size_t)sr.x * 512 + 128 + i * 3];
            float dotv = xv[0] * ya.y + xv[1] * ya.z + xv[2] * ya.w;
            atomicAdd(&M0[(size_t)sr.y * 256 + 128 + i], wval * dotv * INV_SQRT3F);
          }
        }
      }
    }
  }
}

// ---------------------------------------------------------------------------
// Node post-pass: msg_s = M0 @ W_lin0 / 256 ; msg_v[.,j,c] = sum_i M1[.,i,c]*W_lin1[i,j]/256
// out[n*512 + j*4 + 0] = msg_s ; out[n*512 + j*4 + 1 + c] = msg_v
// 16 nodes per block, 512 threads: p = t>>7 (0: scalar, 1..3: vector comp c=p-1)
// ---------------------------------------------------------------------------
__global__ __launch_bounds__(512) void node_post(
    const float* __restrict__ M0, const float* __restrict__ M1,
    const float* __restrict__ W_lin0, const float* __restrict__ W_lin1,
    float* __restrict__ out) {
  __shared__ float ls[16 * 1024];
  const int n0 = blockIdx.x * 16;
  const int t = threadIdx.x;
  for (int f = t; f < 16 * 256; f += 512) {
    int r = f >> 8, c = f & 255;
    ls[r * 1024 + c] = M0[(size_t)(n0 + r) * 256 + c];
  }
  for (int f = t; f < 16 * 768; f += 512) {
    int r = f / 768, c = f % 768;
    ls[r * 1024 + 256 + c] = M1[(size_t)(n0 + r) * 768 + c];
  }
  __syncthreads();
  const int j = t & 127, p = t >> 7;
  float acc[16];
#pragma unroll
  for (int r = 0; r < 16; ++r) acc[r] = 0.f;
  if (p == 0) {
    for (int i = 0; i < 256; ++i) {
      float w = W_lin0[(size_t)i * 128 + j];
#pragma unroll
      for (int r = 0; r < 16; ++r) acc[r] += ls[r * 1024 + i] * w;
    }
#pragma unroll
    for (int r = 0; r < 16; ++r)
      out[(size_t)(n0 + r) * 512 + j * 4] = acc[r] * (1.f / 256.f);
  } else {
    const int c = p - 1;
    for (int i = 0; i < 256; ++i) {
      float w = W_lin1[(size_t)i * 128 + j];
#pragma unroll
      for (int r = 0; r < 16; ++r) acc[r] += ls[r * 1024 + 256 + i * 3 + c] * w;
    }
#pragma unroll
    for (int r = 0; r < 16; ++r)
      out[(size_t)(n0 + r) * 512 + j * 4 + 1 + c] = acc[r] * (1.f / 256.f);
  }
}

// ---------------------------------------------------------------------------
extern "C" void kernel_launch(void* const* d_in, const int* in_sizes, int n_in,
                              void* d_out, int out_size, void* d_ws, size_t ws_size,
                              hipStream_t stream) {
  const float* node_feats = (const float*)d_in[1];
  const float* edge_attrs = (const float*)d_in[2];
  const float* edge_feats = (const float*)d_in[3];
  const int*   edge_index = (const int*)d_in[4];
  const float* W_up0   = (const float*)d_in[5];
  const float* W_up1   = (const float*)d_in[6];
  const float* W_down  = (const float*)d_in[7];
  const float* Wm0     = (const float*)d_in[8];
  const float* Wm1     = (const float*)d_in[9];
  const float* Wm2     = (const float*)d_in[10];
  const float* Wm3     = (const float*)d_in[11];
  const float* W_lin0  = (const float*)d_in[12];
  const float* W_lin1  = (const float*)d_in[13];
  const float* W_skip0 = (const float*)d_in[14];
  const float* W_skip1 = (const float*)d_in[15];
  float* out = (float*)d_out;

  char* ws = (char*)d_ws;
  size_t off = 0;
  auto alloc = [&](size_t bytes) {
    void* p = ws + off;
    off = (off + bytes + 255) & ~(size_t)255;
    return p;
  };
  float*    UP    = (float*)alloc((size_t)NN * 512 * 4);   // up_s | up_v (node_feats layout)
  float*    M0    = (float*)alloc((size_t)NN * 1024 * 4);  // m0 (256) then m1 (768) per node
  float*    M1    = M0 + (size_t)NN * 256;
  _Float16* DOWNH = (_Float16*)alloc((size_t)NN * 64 * 2);
  _Float16* W0h   = (_Float16*)alloc(160 * 256 * 2);
  _Float16* W1h   = (_Float16*)alloc(256 * 256 * 2);
  _Float16* W2h   = (_Float16*)alloc(256 * 256 * 2);
  _Float16* W3h   = (_Float16*)alloc(256 * 512 * 2);

  hipMemsetAsync(M0, 0, (size_t)NN * 1024 * 4, stream);
  // scales folded into fp16 weights: 1/sqrt(136) for layer0, 1/16 for 1..3
  wconv<<<160, 256, 0, stream>>>(Wm0, W0h, 136, 160, 256, 1.0f / sqrtf(136.0f));
  wconv<<<256, 256, 0, stream>>>(Wm1, W1h, 256, 256, 256, 0.0625f);
  wconv<<<256, 256, 0, stream>>>(Wm2, W2h, 256, 256, 256, 0.0625f);
  wconv<<<512, 256, 0, stream>>>(Wm3, W3h, 256, 256, 512, 0.0625f);

  node_pre<<<dim3(625, 5), 256, 0, stream>>>(node_feats, W_up0, W_up1, W_skip0,
                                             W_skip1, W_down, UP, DOWNH,
                                             out + (size_t)NN * 512);
  edge_mlp<<<2500, 256, 0, stream>>>(edge_attrs, edge_feats, edge_index, DOWNH,
                                     UP, W0h, W1h, W2h, W3h, M0, M1);
  node_post<<<625, 512, 0, stream>>>(M0, M1, W_lin0, W_lin1, out);
}

// Round 2
// 1125.250 us; speedup vs baseline: 1.4911x; 1.4911x over previous
//
#include <hip/hip_runtime.h>
#include <cmath>

#define NN 10000
#define NE 160000
#define INV_SQRT_C 0.08838834764831845f   // 1/sqrt(128)
#define INV_SQRT3F 0.5773502691896258f

typedef _Float16 f16x8 __attribute__((ext_vector_type(8)));
typedef _Float16 f16x2 __attribute__((ext_vector_type(2)));
typedef float    f32x4 __attribute__((ext_vector_type(4)));

__device__ __forceinline__ float silu_f(float x) {
  return x / (1.f + __expf(-x));
}

// ---------------------------------------------------------------------------
// Weight conversion fp32 -> fp16, swizzled for MFMA B-fragments:
//   dst[(kb*N + n)*32 + kk] = src[k*N + n] * scale,  k = kb*32 + kk (0 if k>=Korig)
// ---------------------------------------------------------------------------
__global__ void wconv(const float* __restrict__ src, _Float16* __restrict__ dst,
                      int Korig, int Kpad, int N, float scale) {
  int total = Kpad * N;
  for (int t = blockIdx.x * blockDim.x + threadIdx.x; t < total;
       t += gridDim.x * blockDim.x) {
    int n = t % N;
    int k = t / N;
    int kb = k >> 5, kk = k & 31;
    float v = (k < Korig) ? src[(size_t)k * N + n] * scale : 0.f;
    dst[((size_t)(kb * N + n) << 5) + kk] = (_Float16)v;
  }
}

// ---------------------------------------------------------------------------
// Node pre-pass (unchanged from round 1, verified): up_s/up_v -> UP,
// sc -> out upper half, down -> DOWNH (fp16).
// ---------------------------------------------------------------------------
__global__ __launch_bounds__(256) void node_pre(
    const float* __restrict__ feats,
    const float* __restrict__ W_up0, const float* __restrict__ W_up1,
    const float* __restrict__ W_skip0, const float* __restrict__ W_skip1,
    const float* __restrict__ W_down,
    float* __restrict__ UP, _Float16* __restrict__ DOWNH,
    float* __restrict__ out_sc) {
  __shared__ float ls[16 * 384];
  const int y = blockIdx.y;
  const int n0 = blockIdx.x * 16;
  const int t = threadIdx.x;

  if (y == 0 || y == 2 || y == 4) {
    for (int f = t; f < 16 * 128; f += 256) {
      int r = f >> 7, c = f & 127;
      ls[r * 128 + c] = feats[(size_t)(n0 + r) * 512 + c];
    }
    __syncthreads();
    if (y == 4) {
      int j = t & 63, g = t >> 6;
      float acc[4] = {0.f, 0.f, 0.f, 0.f};
      for (int i = 0; i < 128; ++i) {
        float w = W_down[(size_t)i * 64 + j];
#pragma unroll
        for (int r = 0; r < 4; ++r) acc[r] += ls[(g * 4 + r) * 128 + i] * w;
      }
#pragma unroll
      for (int r = 0; r < 4; ++r)
        DOWNH[(size_t)(n0 + g * 4 + r) * 64 + j] = (_Float16)(acc[r] * INV_SQRT_C);
    } else {
      const float* W = (y == 0) ? W_up0 : W_skip0;
      int j = t & 127, g = t >> 7;
      float acc[8] = {0.f, 0.f, 0.f, 0.f, 0.f, 0.f, 0.f, 0.f};
      for (int i = 0; i < 128; ++i) {
        float w = W[(size_t)i * 128 + j];
#pragma unroll
        for (int r = 0; r < 8; ++r) acc[r] += ls[(g * 8 + r) * 128 + i] * w;
      }
#pragma unroll
      for (int r = 0; r < 8; ++r) {
        int n = n0 + g * 8 + r;
        float v = acc[r] * INV_SQRT_C;
        if (y == 0) UP[(size_t)n * 512 + j] = v;
        else        out_sc[(size_t)n * 512 + j] = v;
      }
    }
  } else {
    for (int f = t; f < 16 * 384; f += 256) {
      int r = f / 384, c = f % 384;
      ls[r * 384 + c] = feats[(size_t)(n0 + r) * 512 + 128 + c];
    }
    __syncthreads();
    const float* W = (y == 1) ? W_up1 : W_skip1;
    int j = t & 127, g = t >> 7;
    float acc[8][3];
#pragma unroll
    for (int r = 0; r < 8; ++r)
#pragma unroll
      for (int c = 0; c < 3; ++c) acc[r][c] = 0.f;
    for (int i = 0; i < 128; ++i) {
      float w = W[(size_t)i * 128 + j];
#pragma unroll
      for (int r = 0; r < 8; ++r) {
#pragma unroll
        for (int c = 0; c < 3; ++c)
          acc[r][c] += ls[(g * 8 + r) * 384 + i * 3 + c] * w;
      }
    }
#pragma unroll
    for (int r = 0; r < 8; ++r) {
      int n = n0 + g * 8 + r;
#pragma unroll
      for (int c = 0; c < 3; ++c) {
        float v = acc[r][c] * INV_SQRT_C;
        if (y == 1) UP[(size_t)n * 512 + 128 + j * 3 + c] = v;
        else        out_sc[(size_t)n * 512 + 128 + j * 3 + c] = v;
      }
    }
  }
}

// ---------------------------------------------------------------------------
// CSR build: count per-receiver degree, exclusive scan, fill edge list.
// ---------------------------------------------------------------------------
__global__ void k_count(const int* __restrict__ edge_index, int* __restrict__ CNT) {
  int e = blockIdx.x * blockDim.x + threadIdx.x;
  if (e < NE) atomicAdd(&CNT[edge_index[e * 2 + 1]], 1);
}

__global__ __launch_bounds__(1024) void k_scan(const int* __restrict__ CNT,
                                               int* __restrict__ OFF,
                                               int* __restrict__ CUR) {
  __shared__ int ts[1024];
  const int t = threadIdx.x;
  const int base = t * 10;
  int loc[10];
  int s = 0;
#pragma unroll
  for (int i = 0; i < 10; ++i) {
    int idx = base + i;
    int v = (idx < NN) ? CNT[idx] : 0;
    loc[i] = s;
    s += v;
  }
  ts[t] = s;
  __syncthreads();
  for (int off = 1; off < 1024; off <<= 1) {
    int v = (t >= off) ? ts[t - off] : 0;
    __syncthreads();
    ts[t] += v;
    __syncthreads();
  }
  int tp = (t > 0) ? ts[t - 1] : 0;
#pragma unroll
  for (int i = 0; i < 10; ++i) {
    int idx = base + i;
    if (idx < NN) {
      OFF[idx] = tp + loc[i];
      CUR[idx] = tp + loc[i];
    }
  }
  if (t == 1023) OFF[NN] = ts[1023];
}

__global__ void k_fill(const int* __restrict__ edge_index, int* __restrict__ CUR,
                       int* __restrict__ EIDX) {
  int e = blockIdx.x * blockDim.x + threadIdx.x;
  if (e < NE) {
    int r = edge_index[e * 2 + 1];
    int pos = atomicAdd(&CUR[r], 1);
    EIDX[pos] = e;
  }
}

// ---------------------------------------------------------------------------
// Fused edge kernel: 4-layer MLP (fp16 MFMA) + tensor product + folded
// W_lin GEMMs, writes per-edge 512-fp16 message contribution (no atomics).
// 64 edges/block, 256 threads (4 waves). LDS swizzle:
//   idx(row,col) = row*256 + (((col>>4) ^ (row&15))<<4) + (col&15)
// ---------------------------------------------------------------------------
__device__ __forceinline__ void mlp_layer_256(
    const _Float16* In, _Float16* Out, const _Float16* __restrict__ Wz,
    int m, int g, int wv) {
  f32x4 acc[4][4];
  f32x4 zero4 = {0.f, 0.f, 0.f, 0.f};
#pragma unroll
  for (int rt = 0; rt < 4; ++rt)
#pragma unroll
    for (int ct = 0; ct < 4; ++ct) acc[rt][ct] = zero4;

#pragma unroll
  for (int kb = 0; kb < 8; ++kb) {
    f16x8 a[4], b[4];
#pragma unroll
    for (int rt = 0; rt < 4; ++rt) {
      int row = rt * 16 + m;
      a[rt] = *(const f16x8*)&In[row * 256 + (((kb * 2 + (g >> 1)) ^ m) << 4) + (g & 1) * 8];
    }
#pragma unroll
    for (int ct = 0; ct < 4; ++ct)
      b[ct] = *(const f16x8*)&Wz[((size_t)(kb * 256 + wv * 64 + ct * 16 + m) << 5) + g * 8];
#pragma unroll
    for (int rt = 0; rt < 4; ++rt)
#pragma unroll
      for (int ct = 0; ct < 4; ++ct)
        acc[rt][ct] = __builtin_amdgcn_mfma_f32_16x16x32_f16(a[rt], b[ct], acc[rt][ct], 0, 0, 0);
  }
#pragma unroll
  for (int rt = 0; rt < 4; ++rt)
#pragma unroll
    for (int ct = 0; ct < 4; ++ct)
#pragma unroll
      for (int q = 0; q < 4; ++q) {
        int row = rt * 16 + g * 4 + q;
        float s = silu_f(acc[rt][ct][q]);
        Out[row * 256 + (((wv * 4 + ct) ^ (g * 4 + q)) << 4) + m] = (_Float16)s;
      }
}

// folded W_lin GEMM: S (64x256 fp16, A-swizzled) @ WLh (256->128) -> MIDs[:, xbase+j]
__device__ __forceinline__ void fold_gemm(
    const _Float16* S, const _Float16* __restrict__ WLh,
    _Float16* __restrict__ MIDs, int e0, int xbase, int m, int g, int wv) {
  f32x4 acc[4][2];
  f32x4 zero4 = {0.f, 0.f, 0.f, 0.f};
#pragma unroll
  for (int rt = 0; rt < 4; ++rt)
#pragma unroll
    for (int ct = 0; ct < 2; ++ct) acc[rt][ct] = zero4;
#pragma unroll
  for (int kb = 0; kb < 8; ++kb) {
    f16x8 a[4], b[2];
#pragma unroll
    for (int rt = 0; rt < 4; ++rt)
      a[rt] = *(const f16x8*)&S[(rt * 16 + m) * 256 + (((kb * 2 + (g >> 1)) ^ m) << 4) + (g & 1) * 8];
#pragma unroll
    for (int ct = 0; ct < 2; ++ct)
      b[ct] = *(const f16x8*)&WLh[((size_t)(kb * 128 + wv * 32 + ct * 16 + m) << 5) + g * 8];
#pragma unroll
    for (int rt = 0; rt < 4; ++rt)
#pragma unroll
      for (int ct = 0; ct < 2; ++ct)
        acc[rt][ct] = __builtin_amdgcn_mfma_f32_16x16x32_f16(a[rt], b[ct], acc[rt][ct], 0, 0, 0);
  }
#pragma unroll
  for (int rt = 0; rt < 4; ++rt)
#pragma unroll
    for (int ct = 0; ct < 2; ++ct)
#pragma unroll
      for (int q = 0; q < 4; ++q) {
        int el = e0 + rt * 16 + g * 4 + q;
        int j = wv * 32 + ct * 16 + m;
        MIDs[(size_t)el * 512 + xbase + j] = (_Float16)acc[rt][ct][q];
      }
}

// stage mid1 plane c into S: cols [0,128)=out1a (waves 2,3), [128,256)=out1b (waves 0,1)
__device__ __forceinline__ void stage_plane(
    _Float16* S, const f32x4 (&acc0)[4][4], const f32x4 (&acc1)[4][4],
    const int* __restrict__ edge_index, const float* __restrict__ edge_attrs,
    const float* __restrict__ UP, int e0, int m, int g, int wv, int nw, int c) {
#pragma unroll
  for (int rt = 0; rt < 4; ++rt) {
#pragma unroll
    for (int q = 0; q < 4; ++q) {
      int elo = rt * 16 + g * 4 + q;
      int el = e0 + elo;
      int2 sr = *(const int2*)&edge_index[(size_t)el * 2];
      float4 ya = *(const float4*)&edge_attrs[(size_t)el * 4];
      float yv[3] = {ya.y, ya.z, ya.w};
#pragma unroll
      for (int ct = 0; ct < 4; ++ct) {
        int scol;
        float v;
        if (wv < 2) {                    // w3: out1b[i][c] = w3 * xv[i][c] * y0
          int i = nw + ct * 16 + m;      // 0..127
          float xvc = UP[(size_t)sr.x * 512 + 128 + i * 3 + c];
          v = acc1[rt][ct][q] * xvc * ya.x;
          scol = 128 + i;
        } else {                         // w2: out1a[i][c] = w2 * xs[i] * yv[c]
          int i = (nw - 128) + ct * 16 + m;
          float xs = UP[(size_t)sr.x * 512 + i];
          v = acc0[rt][ct][q] * xs * yv[c];
          scol = i;
        }
        S[elo * 256 + (((scol >> 4) ^ (g * 4 + q)) << 4) + m] = (_Float16)v;
      }
    }
  }
}

__global__ __launch_bounds__(256, 2) void edge_mlp(
    const float* __restrict__ edge_attrs,
    const float* __restrict__ edge_feats,
    const int* __restrict__ edge_index,
    const _Float16* __restrict__ DOWNH,
    const float* __restrict__ UP,
    const _Float16* __restrict__ W0h, const _Float16* __restrict__ W1h,
    const _Float16* __restrict__ W2h, const _Float16* __restrict__ W3h,
    const _Float16* __restrict__ WL0h, const _Float16* __restrict__ WL1h,
    _Float16* __restrict__ MIDs) {
  __shared__ _Float16 HA[64 * 256];
  __shared__ _Float16 HB[64 * 256];

  const int tid = threadIdx.x;
  const int lane = tid & 63;
  const int wv = tid >> 6;
  const int m = lane & 15;
  const int g = lane >> 4;
  const int e0 = blockIdx.x * 64;
  const int nw = wv * 64;

  int snd_r[4], rcv_r[4];
#pragma unroll
  for (int rt = 0; rt < 4; ++rt) {
    int2 sr = *(const int2*)&edge_index[(size_t)(e0 + rt * 16 + m) * 2];
    snd_r[rt] = sr.x;
    rcv_r[rt] = sr.y;
  }

  f32x4 zero4 = {0.f, 0.f, 0.f, 0.f};
  f16x8 zf = {0, 0, 0, 0, 0, 0, 0, 0};

  // ---------------- layer 0: aug(136, padded 160) -> h1 (HA)
  {
    f32x4 acc[4][4];
#pragma unroll
    for (int rt = 0; rt < 4; ++rt)
#pragma unroll
      for (int ct = 0; ct < 4; ++ct) acc[rt][ct] = zero4;

#pragma unroll
    for (int kb = 0; kb < 5; ++kb) {
      const int k0 = kb * 32 + g * 8;
      f16x8 a[4], b[4];
#pragma unroll
      for (int rt = 0; rt < 4; ++rt) {
        if (k0 == 0) {
          const float* ef = &edge_feats[(size_t)(e0 + rt * 16 + m) * 8];
          float4 f0 = *(const float4*)ef;
          float4 f1 = *(const float4*)(ef + 4);
          f16x8 av;
          av[0] = (_Float16)f0.x; av[1] = (_Float16)f0.y;
          av[2] = (_Float16)f0.z; av[3] = (_Float16)f0.w;
          av[4] = (_Float16)f1.x; av[5] = (_Float16)f1.y;
          av[6] = (_Float16)f1.z; av[7] = (_Float16)f1.w;
          a[rt] = av;
        } else if (k0 < 72) {
          a[rt] = *(const f16x8*)&DOWNH[(size_t)snd_r[rt] * 64 + (k0 - 8)];
        } else if (k0 < 136) {
          a[rt] = *(const f16x8*)&DOWNH[(size_t)rcv_r[rt] * 64 + (k0 - 72)];
        } else {
          a[rt] = zf;
        }
      }
#pragma unroll
      for (int ct = 0; ct < 4; ++ct)
        b[ct] = *(const f16x8*)&W0h[((size_t)(kb * 256 + nw + ct * 16 + m) << 5) + g * 8];
#pragma unroll
      for (int rt = 0; rt < 4; ++rt)
#pragma unroll
        for (int ct = 0; ct < 4; ++ct)
          acc[rt][ct] = __builtin_amdgcn_mfma_f32_16x16x32_f16(a[rt], b[ct], acc[rt][ct], 0, 0, 0);
    }
#pragma unroll
    for (int rt = 0; rt < 4; ++rt)
#pragma unroll
      for (int ct = 0; ct < 4; ++ct)
#pragma unroll
        for (int q = 0; q < 4; ++q) {
          int row = rt * 16 + g * 4 + q;
          float s = silu_f(acc[rt][ct][q]);
          HA[row * 256 + (((wv * 4 + ct) ^ (g * 4 + q)) << 4) + m] = (_Float16)s;
        }
  }
  __syncthreads();

  mlp_layer_256(HA, HB, W1h, m, g, wv);   // layer 1
  __syncthreads();
  mlp_layer_256(HB, HA, W2h, m, g, wv);   // layer 2 (h3 -> HA)
  __syncthreads();

  // ---------------- layer 3: h3 -> tpw (both halves in registers)
  f32x4 acc3[2][4][4];
#pragma unroll
  for (int h = 0; h < 2; ++h)
#pragma unroll
    for (int rt = 0; rt < 4; ++rt)
#pragma unroll
      for (int ct = 0; ct < 4; ++ct) acc3[h][rt][ct] = zero4;

#pragma unroll
  for (int kb = 0; kb < 8; ++kb) {
    f16x8 a[4];
#pragma unroll
    for (int rt = 0; rt < 4; ++rt) {
      int row = rt * 16 + m;
      a[rt] = *(const f16x8*)&HA[row * 256 + (((kb * 2 + (g >> 1)) ^ m) << 4) + (g & 1) * 8];
    }
#pragma unroll
    for (int h = 0; h < 2; ++h) {
      f16x8 b[4];
#pragma unroll
      for (int ct = 0; ct < 4; ++ct)
        b[ct] = *(const f16x8*)&W3h[((size_t)(kb * 512 + h * 256 + nw + ct * 16 + m) << 5) + g * 8];
#pragma unroll
      for (int rt = 0; rt < 4; ++rt)
#pragma unroll
        for (int ct = 0; ct < 4; ++ct)
          acc3[h][rt][ct] = __builtin_amdgcn_mfma_f32_16x16x32_f16(a[rt], b[ct], acc3[h][rt][ct], 0, 0, 0);
    }
  }
  __syncthreads();  // all waves done reading HA (h3)

  // P0: stage mid0 into HA: cols [0,128)=w1*xs*y0 (waves 0,1),
  //     cols [128,256)=w4*dot(xv,yv)/sqrt3 (waves 2,3)
#pragma unroll
  for (int rt = 0; rt < 4; ++rt) {
#pragma unroll
    for (int q = 0; q < 4; ++q) {
      int elo = rt * 16 + g * 4 + q;
      int el = e0 + elo;
      int2 sr = *(const int2*)&edge_index[(size_t)el * 2];
      float4 ya = *(const float4*)&edge_attrs[(size_t)el * 4];
#pragma unroll
      for (int ct = 0; ct < 4; ++ct) {
        int scol = nw + ct * 16 + m;
        float v;
        if (wv < 2) {
          float xs = UP[(size_t)sr.x * 512 + scol];
          v = acc3[0][rt][ct][q] * xs * ya.x;
        } else {
          int i = scol - 128;
          float xv0 = UP[(size_t)sr.x * 512 + 128 + i * 3 + 0];
          float xv1 = UP[(size_t)sr.x * 512 + 128 + i * 3 + 1];
          float xv2 = UP[(size_t)sr.x * 512 + 128 + i * 3 + 2];
          v = acc3[1][rt][ct][q] * (xv0 * ya.y + xv1 * ya.z + xv2 * ya.w) * INV_SQRT3F;
        }
        HA[elo * 256 + (((scol >> 4) ^ (g * 4 + q)) << 4) + m] = (_Float16)v;
      }
    }
  }
  __syncthreads();

  // P1: stage plane0 -> HB ; GEMM(HA @ WL0h) -> MIDs[:, 0..127]
  stage_plane(HB, acc3[0], acc3[1], edge_index, edge_attrs, UP, e0, m, g, wv, nw, 0);
  fold_gemm(HA, WL0h, MIDs, e0, 0, m, g, wv);
  __syncthreads();
  // P2: stage plane1 -> HA ; GEMM(HB @ WL1h) -> MIDs[:, 128..255]
  stage_plane(HA, acc3[0], acc3[1], edge_index, edge_attrs, UP, e0, m, g, wv, nw, 1);
  fold_gemm(HB, WL1h, MIDs, e0, 128, m, g, wv);
  __syncthreads();
  // P3: stage plane2 -> HB ; GEMM(HA @ WL1h) -> MIDs[:, 256..383]
  stage_plane(HB, acc3[0], acc3[1], edge_index, edge_attrs, UP, e0, m, g, wv, nw, 2);
  fold_gemm(HA, WL1h, MIDs, e0, 256, m, g, wv);
  __syncthreads();
  // P4: GEMM(HB @ WL1h) -> MIDs[:, 384..511]
  fold_gemm(HB, WL1h, MIDs, e0, 384, m, g, wv);
}

// ---------------------------------------------------------------------------
// Gather: one block per node, sum per-edge message contributions (fp32 acc),
// write interleaved output: x<128 -> msg_s[x]; else c=(x-128)>>7, j=(x-128)&127
// ---------------------------------------------------------------------------
__global__ __launch_bounds__(256) void gather_msg(
    const _Float16* __restrict__ MIDs, const int* __restrict__ OFF,
    const int* __restrict__ EIDX, float* __restrict__ out) {
  const int n = blockIdx.x;
  const int t = threadIdx.x;
  const int beg = OFF[n], end = OFF[n + 1];
  float a0 = 0.f, a1 = 0.f;
  for (int k = beg; k < end; ++k) {
    int e = EIDX[k];
    f16x2 v = *(const f16x2*)&MIDs[(size_t)e * 512 + t * 2];
    a0 += (float)v[0];
    a1 += (float)v[1];
  }
#pragma unroll
  for (int u = 0; u < 2; ++u) {
    int x = t * 2 + u;
    float a = u ? a1 : a0;
    int dst;
    if (x < 128) {
      dst = n * 512 + x * 4;
    } else {
      int xm = x - 128;
      int c = xm >> 7, j = xm & 127;
      dst = n * 512 + j * 4 + 1 + c;
    }
    out[dst] = a;
  }
}

// ---------------------------------------------------------------------------
extern "C" void kernel_launch(void* const* d_in, const int* in_sizes, int n_in,
                              void* d_out, int out_size, void* d_ws, size_t ws_size,
                              hipStream_t stream) {
  const float* node_feats = (const float*)d_in[1];
  const float* edge_attrs = (const float*)d_in[2];
  const float* edge_feats = (const float*)d_in[3];
  const int*   edge_index = (const int*)d_in[4];
  const float* W_up0   = (const float*)d_in[5];
  const float* W_up1   = (const float*)d_in[6];
  const float* W_down  = (const float*)d_in[7];
  const float* Wm0     = (const float*)d_in[8];
  const float* Wm1     = (const float*)d_in[9];
  const float* Wm2     = (const float*)d_in[10];
  const float* Wm3     = (const float*)d_in[11];
  const float* W_lin0  = (const float*)d_in[12];
  const float* W_lin1  = (const float*)d_in[13];
  const float* W_skip0 = (const float*)d_in[14];
  const float* W_skip1 = (const float*)d_in[15];
  float* out = (float*)d_out;

  char* ws = (char*)d_ws;
  size_t off = 0;
  auto alloc = [&](size_t bytes) {
    void* p = ws + off;
    off = (off + bytes + 255) & ~(size_t)255;
    return p;
  };
  float*    UP    = (float*)alloc((size_t)NN * 512 * 4);
  _Float16* DOWNH = (_Float16*)alloc((size_t)NN * 64 * 2);
  _Float16* W0h   = (_Float16*)alloc(160 * 256 * 2);
  _Float16* W1h   = (_Float16*)alloc(256 * 256 * 2);
  _Float16* W2h   = (_Float16*)alloc(256 * 256 * 2);
  _Float16* W3h   = (_Float16*)alloc(256 * 512 * 2);
  _Float16* WL0h  = (_Float16*)alloc(256 * 128 * 2);
  _Float16* WL1h  = (_Float16*)alloc(256 * 128 * 2);
  int*      CNT   = (int*)alloc((size_t)NN * 4);
  int*      OFF   = (int*)alloc((size_t)(NN + 1) * 4);
  int*      CUR   = (int*)alloc((size_t)NN * 4);
  int*      EIDX  = (int*)alloc((size_t)NE * 4);
  _Float16* MIDs  = (_Float16*)alloc((size_t)NE * 512 * 2);

  hipMemsetAsync(CNT, 0, (size_t)NN * 4, stream);

  // scales folded into fp16 weights: 1/sqrt(136) layer0, 1/16 layers 1..3,
  // 1/(sqrt(256)*16)=1/256 for W_lin (includes AVG_NEIGH)
  wconv<<<160, 256, 0, stream>>>(Wm0, W0h, 136, 160, 256, 1.0f / sqrtf(136.0f));
  wconv<<<256, 256, 0, stream>>>(Wm1, W1h, 256, 256, 256, 0.0625f);
  wconv<<<256, 256, 0, stream>>>(Wm2, W2h, 256, 256, 256, 0.0625f);
  wconv<<<512, 256, 0, stream>>>(Wm3, W3h, 256, 256, 512, 0.0625f);
  wconv<<<128, 256, 0, stream>>>(W_lin0, WL0h, 256, 256, 128, 1.0f / 256.0f);
  wconv<<<128, 256, 0, stream>>>(W_lin1, WL1h, 256, 256, 128, 1.0f / 256.0f);

  node_pre<<<dim3(625, 5), 256, 0, stream>>>(node_feats, W_up0, W_up1, W_skip0,
                                             W_skip1, W_down, UP, DOWNH,
                                             out + (size_t)NN * 512);
  k_count<<<625, 256, 0, stream>>>(edge_index, CNT);
  k_scan<<<1, 1024, 0, stream>>>(CNT, OFF, CUR);
  k_fill<<<625, 256, 0, stream>>>(edge_index, CUR, EIDX);

  edge_mlp<<<2500, 256, 0, stream>>>(edge_attrs, edge_feats, edge_index, DOWNH,
                                     UP, W0h, W1h, W2h, W3h, WL0h, WL1h, MIDs);
  gather_msg<<<NN, 256, 0, stream>>>(MIDs, OFF, EIDX, out);
}

// Round 3
// 664.122 us; speedup vs baseline: 2.5264x; 1.6943x over previous
//
#include <hip/hip_runtime.h>
#include <cmath>

#define NN 10000
#define NE 160000
#define INV_SQRT_C 0.08838834764831845f   // 1/sqrt(128)
#define INV_SQRT3F 0.5773502691896258f

typedef _Float16 f16x8 __attribute__((ext_vector_type(8)));
typedef _Float16 f16x2 __attribute__((ext_vector_type(2)));
typedef float    f32x4 __attribute__((ext_vector_type(4)));

__device__ __forceinline__ float silu_f(float x) {
  return x / (1.f + __expf(-x));
}

// ---------------------------------------------------------------------------
// Weight conversion fp32 -> fp16, swizzled for MFMA B-fragments:
//   dst[(kb*N + n)*32 + kk] = src[k*N + n] * scale,  k = kb*32 + kk (0 if k>=Korig)
// ---------------------------------------------------------------------------
__global__ void wconv(const float* __restrict__ src, _Float16* __restrict__ dst,
                      int Korig, int Kpad, int N, float scale) {
  int total = Kpad * N;
  for (int t = blockIdx.x * blockDim.x + threadIdx.x; t < total;
       t += gridDim.x * blockDim.x) {
    int n = t % N;
    int k = t / N;
    int kb = k >> 5, kk = k & 31;
    float v = (k < Korig) ? src[(size_t)k * N + n] * scale : 0.f;
    dst[((size_t)(kb * N + n) << 5) + kk] = (_Float16)v;
  }
}

// ---------------------------------------------------------------------------
// Node pre-pass: up_s/up_v -> UPH (fp16, row layout [s(128) | v(384 interleaved)]),
// sc -> out upper half (fp32), down -> DOWNH (fp16).
// ---------------------------------------------------------------------------
__global__ __launch_bounds__(256) void node_pre(
    const float* __restrict__ feats,
    const float* __restrict__ W_up0, const float* __restrict__ W_up1,
    const float* __restrict__ W_skip0, const float* __restrict__ W_skip1,
    const float* __restrict__ W_down,
    _Float16* __restrict__ UPH, _Float16* __restrict__ DOWNH,
    float* __restrict__ out_sc) {
  __shared__ float ls[16 * 384];
  const int y = blockIdx.y;
  const int n0 = blockIdx.x * 16;
  const int t = threadIdx.x;

  if (y == 0 || y == 2 || y == 4) {
    for (int f = t; f < 16 * 128; f += 256) {
      int r = f >> 7, c = f & 127;
      ls[r * 128 + c] = feats[(size_t)(n0 + r) * 512 + c];
    }
    __syncthreads();
    if (y == 4) {
      int j = t & 63, g = t >> 6;
      float acc[4] = {0.f, 0.f, 0.f, 0.f};
      for (int i = 0; i < 128; ++i) {
        float w = W_down[(size_t)i * 64 + j];
#pragma unroll
        for (int r = 0; r < 4; ++r) acc[r] += ls[(g * 4 + r) * 128 + i] * w;
      }
#pragma unroll
      for (int r = 0; r < 4; ++r)
        DOWNH[(size_t)(n0 + g * 4 + r) * 64 + j] = (_Float16)(acc[r] * INV_SQRT_C);
    } else {
      const float* W = (y == 0) ? W_up0 : W_skip0;
      int j = t & 127, g = t >> 7;
      float acc[8] = {0.f, 0.f, 0.f, 0.f, 0.f, 0.f, 0.f, 0.f};
      for (int i = 0; i < 128; ++i) {
        float w = W[(size_t)i * 128 + j];
#pragma unroll
        for (int r = 0; r < 8; ++r) acc[r] += ls[(g * 8 + r) * 128 + i] * w;
      }
#pragma unroll
      for (int r = 0; r < 8; ++r) {
        int n = n0 + g * 8 + r;
        float v = acc[r] * INV_SQRT_C;
        if (y == 0) UPH[(size_t)n * 512 + j] = (_Float16)v;
        else        out_sc[(size_t)n * 512 + j] = v;
      }
    }
  } else {
    for (int f = t; f < 16 * 384; f += 256) {
      int r = f / 384, c = f % 384;
      ls[r * 384 + c] = feats[(size_t)(n0 + r) * 512 + 128 + c];
    }
    __syncthreads();
    const float* W = (y == 1) ? W_up1 : W_skip1;
    int j = t & 127, g = t >> 7;
    float acc[8][3];
#pragma unroll
    for (int r = 0; r < 8; ++r)
#pragma unroll
      for (int c = 0; c < 3; ++c) acc[r][c] = 0.f;
    for (int i = 0; i < 128; ++i) {
      float w = W[(size_t)i * 128 + j];
#pragma unroll
      for (int r = 0; r < 8; ++r) {
#pragma unroll
        for (int c = 0; c < 3; ++c)
          acc[r][c] += ls[(g * 8 + r) * 384 + i * 3 + c] * w;
      }
    }
#pragma unroll
    for (int r = 0; r < 8; ++r) {
      int n = n0 + g * 8 + r;
#pragma unroll
      for (int c = 0; c < 3; ++c) {
        float v = acc[r][c] * INV_SQRT_C;
        if (y == 1) UPH[(size_t)n * 512 + 128 + j * 3 + c] = (_Float16)v;
        else        out_sc[(size_t)n * 512 + 128 + j * 3 + c] = v;
      }
    }
  }
}

// ---------------------------------------------------------------------------
// CSR build: count per-receiver degree, exclusive scan, fill edge list.
// ---------------------------------------------------------------------------
__global__ void k_count(const int* __restrict__ edge_index, int* __restrict__ CNT) {
  int e = blockIdx.x * blockDim.x + threadIdx.x;
  if (e < NE) atomicAdd(&CNT[edge_index[e * 2 + 1]], 1);
}

__global__ __launch_bounds__(1024) void k_scan(const int* __restrict__ CNT,
                                               int* __restrict__ OFF,
                                               int* __restrict__ CUR) {
  __shared__ int ts[1024];
  const int t = threadIdx.x;
  const int base = t * 10;
  int loc[10];
  int s = 0;
#pragma unroll
  for (int i = 0; i < 10; ++i) {
    int idx = base + i;
    int v = (idx < NN) ? CNT[idx] : 0;
    loc[i] = s;
    s += v;
  }
  ts[t] = s;
  __syncthreads();
  for (int off = 1; off < 1024; off <<= 1) {
    int v = (t >= off) ? ts[t - off] : 0;
    __syncthreads();
    ts[t] += v;
    __syncthreads();
  }
  int tp = (t > 0) ? ts[t - 1] : 0;
#pragma unroll
  for (int i = 0; i < 10; ++i) {
    int idx = base + i;
    if (idx < NN) {
      OFF[idx] = tp + loc[i];
      CUR[idx] = tp + loc[i];
    }
  }
  if (t == 1023) OFF[NN] = ts[1023];
}

__global__ void k_fill(const int* __restrict__ edge_index, int* __restrict__ CUR,
                       int* __restrict__ EIDX) {
  int e = blockIdx.x * blockDim.x + threadIdx.x;
  if (e < NE) {
    int r = edge_index[e * 2 + 1];
    int pos = atomicAdd(&CUR[r], 1);
    EIDX[pos] = e;
  }
}

// ---------------------------------------------------------------------------
// Fused edge kernel. 64 edges/block, 256 threads (4 waves).
// Layers 0-2: MFMA ping-pong HA<->HB (h3 ends in HA, stays live).
// Epilogue per 128-col quarter Q of tpw: quarter GEMM (h3@Wm3[:,Q]) -> regs;
// transpose to SW (row-major via LDS); TP stage: thread owns edge e=tid&63,
// streams UPH[sender] with f16x8 loads, writes A=tpw⊙x to SP; fold GEMM
// (SP@WLpart, k=128); per-edge y-attrs applied AFTER folding (linearity).
// SW/SP (16KB each) overlay dead HB. LDS total 64KB -> 2 blocks/CU.
// Swizzle: blk = ((col>>4) ^ ((row ^ (row>>3)) & 7)) & 7  (LD=128 fp16)
// ---------------------------------------------------------------------------
__device__ __forceinline__ void mlp_layer_256(
    const _Float16* In, _Float16* Out, const _Float16* __restrict__ Wz,
    int m, int g, int wv) {
  f32x4 acc[4][4];
  f32x4 zero4 = {0.f, 0.f, 0.f, 0.f};
#pragma unroll
  for (int rt = 0; rt < 4; ++rt)
#pragma unroll
    for (int ct = 0; ct < 4; ++ct) acc[rt][ct] = zero4;

#pragma unroll
  for (int kb = 0; kb < 8; ++kb) {
    f16x8 a[4], b[4];
#pragma unroll
    for (int rt = 0; rt < 4; ++rt) {
      int row = rt * 16 + m;
      a[rt] = *(const f16x8*)&In[row * 256 + (((kb * 2 + (g >> 1)) ^ m) << 4) + (g & 1) * 8];
    }
#pragma unroll
    for (int ct = 0; ct < 4; ++ct)
      b[ct] = *(const f16x8*)&Wz[((size_t)(kb * 256 + wv * 64 + ct * 16 + m) << 5) + g * 8];
#pragma unroll
    for (int rt = 0; rt < 4; ++rt)
#pragma unroll
      for (int ct = 0; ct < 4; ++ct)
        acc[rt][ct] = __builtin_amdgcn_mfma_f32_16x16x32_f16(a[rt], b[ct], acc[rt][ct], 0, 0, 0);
  }
#pragma unroll
  for (int rt = 0; rt < 4; ++rt)
#pragma unroll
    for (int ct = 0; ct < 4; ++ct)
#pragma unroll
      for (int q = 0; q < 4; ++q) {
        int row = rt * 16 + g * 4 + q;
        float s = silu_f(acc[rt][ct][q]);
        Out[row * 256 + (((wv * 4 + ct) ^ (g * 4 + q)) << 4) + m] = (_Float16)s;
      }
}

__global__ __launch_bounds__(256, 2) void edge_mlp(
    const float* __restrict__ edge_attrs,
    const float* __restrict__ edge_feats,
    const int* __restrict__ edge_index,
    const _Float16* __restrict__ DOWNH,
    const _Float16* __restrict__ UPH,
    const _Float16* __restrict__ W0h, const _Float16* __restrict__ W1h,
    const _Float16* __restrict__ W2h, const _Float16* __restrict__ W3h,
    const _Float16* __restrict__ WL0h, const _Float16* __restrict__ WL1h,
    _Float16* __restrict__ MIDs) {
  __shared__ _Float16 HA[64 * 256];
  __shared__ _Float16 HB[64 * 256];

  const int tid = threadIdx.x;
  const int lane = tid & 63;
  const int wv = tid >> 6;
  const int m = lane & 15;
  const int g = lane >> 4;
  const int e0 = blockIdx.x * 64;
  const int nw = wv * 64;

  int snd_r[4], rcv_r[4];
#pragma unroll
  for (int rt = 0; rt < 4; ++rt) {
    int2 sr = *(const int2*)&edge_index[(size_t)(e0 + rt * 16 + m) * 2];
    snd_r[rt] = sr.x;
    rcv_r[rt] = sr.y;
  }

  f32x4 zero4 = {0.f, 0.f, 0.f, 0.f};
  f16x8 zf = {0, 0, 0, 0, 0, 0, 0, 0};

  // ---------------- layer 0: aug(136, padded 160) -> h1 (HA)
  {
    f32x4 acc[4][4];
#pragma unroll
    for (int rt = 0; rt < 4; ++rt)
#pragma unroll
      for (int ct = 0; ct < 4; ++ct) acc[rt][ct] = zero4;

#pragma unroll
    for (int kb = 0; kb < 5; ++kb) {
      const int k0 = kb * 32 + g * 8;
      f16x8 a[4], b[4];
#pragma unroll
      for (int rt = 0; rt < 4; ++rt) {
        if (k0 == 0) {
          const float* ef = &edge_feats[(size_t)(e0 + rt * 16 + m) * 8];
          float4 f0 = *(const float4*)ef;
          float4 f1 = *(const float4*)(ef + 4);
          f16x8 av;
          av[0] = (_Float16)f0.x; av[1] = (_Float16)f0.y;
          av[2] = (_Float16)f0.z; av[3] = (_Float16)f0.w;
          av[4] = (_Float16)f1.x; av[5] = (_Float16)f1.y;
          av[6] = (_Float16)f1.z; av[7] = (_Float16)f1.w;
          a[rt] = av;
        } else if (k0 < 72) {
          a[rt] = *(const f16x8*)&DOWNH[(size_t)snd_r[rt] * 64 + (k0 - 8)];
        } else if (k0 < 136) {
          a[rt] = *(const f16x8*)&DOWNH[(size_t)rcv_r[rt] * 64 + (k0 - 72)];
        } else {
          a[rt] = zf;
        }
      }
#pragma unroll
      for (int ct = 0; ct < 4; ++ct)
        b[ct] = *(const f16x8*)&W0h[((size_t)(kb * 256 + nw + ct * 16 + m) << 5) + g * 8];
#pragma unroll
      for (int rt = 0; rt < 4; ++rt)
#pragma unroll
        for (int ct = 0; ct < 4; ++ct)
          acc[rt][ct] = __builtin_amdgcn_mfma_f32_16x16x32_f16(a[rt], b[ct], acc[rt][ct], 0, 0, 0);
    }
#pragma unroll
    for (int rt = 0; rt < 4; ++rt)
#pragma unroll
      for (int ct = 0; ct < 4; ++ct)
#pragma unroll
        for (int q = 0; q < 4; ++q) {
          int row = rt * 16 + g * 4 + q;
          float s = silu_f(acc[rt][ct][q]);
          HA[row * 256 + (((wv * 4 + ct) ^ (g * 4 + q)) << 4) + m] = (_Float16)s;
        }
  }
  __syncthreads();

  mlp_layer_256(HA, HB, W1h, m, g, wv);   // layer 1: h1 -> h2
  __syncthreads();
  mlp_layer_256(HB, HA, W2h, m, g, wv);   // layer 2: h2 -> h3 (HA, stays live)
  __syncthreads();

  // ================= epilogue =================
  _Float16* SW = HB;             // 64 x 128 fp16 (16 KB), tpw quarter row-major
  _Float16* SP = HB + 64 * 128;  // 64 x 128 fp16 (16 KB), TP'd A-matrix

  const int e_loc = lane;                       // consumer edge (per wave)
  const int ers = (e_loc ^ (e_loc >> 3)) & 7;   // row swizzle key for e_loc
  const int snd_e = edge_index[(size_t)(e0 + e_loc) * 2];
  const _Float16* uprow = &UPH[(size_t)snd_e * 512];

  f32x4 accq[4][2];

  // quarter GEMM: h3(HA) @ Wm3[:, qbase..qbase+128) -> accq (C/D layout)
  auto qgemm = [&](int qbase) {
#pragma unroll
    for (int rt = 0; rt < 4; ++rt)
#pragma unroll
      for (int ct = 0; ct < 2; ++ct) accq[rt][ct] = zero4;
#pragma unroll
    for (int kb = 0; kb < 8; ++kb) {
      f16x8 a[4], b[2];
#pragma unroll
      for (int rt = 0; rt < 4; ++rt) {
        int row = rt * 16 + m;
        a[rt] = *(const f16x8*)&HA[row * 256 + (((kb * 2 + (g >> 1)) ^ m) << 4) + (g & 1) * 8];
      }
#pragma unroll
      for (int ct = 0; ct < 2; ++ct)
        b[ct] = *(const f16x8*)&W3h[((size_t)(kb * 512 + qbase + wv * 32 + ct * 16 + m) << 5) + g * 8];
#pragma unroll
      for (int rt = 0; rt < 4; ++rt)
#pragma unroll
        for (int ct = 0; ct < 2; ++ct)
          accq[rt][ct] = __builtin_amdgcn_mfma_f32_16x16x32_f16(a[rt], b[ct], accq[rt][ct], 0, 0, 0);
    }
  };

  // transpose accq (C/D) -> SW row-major [64][128] (swizzled), fp16
  auto sw_write = [&]() {
#pragma unroll
    for (int rt = 0; rt < 4; ++rt)
#pragma unroll
      for (int ct = 0; ct < 2; ++ct)
#pragma unroll
        for (int r4 = 0; r4 < 4; ++r4) {
          int row = rt * 16 + g * 4 + r4;
          int rs = (row ^ (row >> 3)) & 7;
          SW[row * 128 + ((((wv * 2 + ct) ^ rs) & 7) << 4) + m] = (_Float16)accq[rt][ct][r4];
        }
  };

  // fold GEMM: SP[64x128] @ WLh[qpart*128.., ->128] -> P (C/D layout)
  auto fold = [&](const _Float16* __restrict__ WLh, int qpart, f32x4 (&P)[4][2]) {
#pragma unroll
    for (int rt = 0; rt < 4; ++rt)
#pragma unroll
      for (int ct = 0; ct < 2; ++ct) P[rt][ct] = zero4;
#pragma unroll
    for (int kb = 0; kb < 4; ++kb) {
      f16x8 a[4], b[2];
#pragma unroll
      for (int rt = 0; rt < 4; ++rt) {
        int row = rt * 16 + m;
        int rs = (row ^ (row >> 3)) & 7;
        a[rt] = *(const f16x8*)&SP[row * 128 + ((((kb * 2 + (g >> 1)) ^ rs) & 7) << 4) + (g & 1) * 8];
      }
#pragma unroll
      for (int ct = 0; ct < 2; ++ct)
        b[ct] = *(const f16x8*)&WLh[((size_t)((qpart * 4 + kb) * 128 + wv * 32 + ct * 16 + m) << 5) + g * 8];
#pragma unroll
      for (int rt = 0; rt < 4; ++rt)
#pragma unroll
        for (int ct = 0; ct < 2; ++ct)
          P[rt][ct] = __builtin_amdgcn_mfma_f32_16x16x32_f16(a[rt], b[ct], P[rt][ct], 0, 0, 0);
    }
  };

  // TP: A = SW[e][i] * xs[i]  (i in [wv*32, wv*32+32))
  auto tp_xs = [&]() {
#pragma unroll
    for (int cch = 0; cch < 4; ++cch) {
      int ib = nw / 2 + cch * 8;  // wv*32 + cch*8
      int blk = ((ib >> 4) ^ ers) & 7;
      int off = e_loc * 128 + (blk << 4) + (ib & 15);
      f16x8 swv = *(const f16x8*)&SW[off];
      f16x8 upv = *(const f16x8*)&uprow[ib];
      f16x8 pr = swv * upv;
      *(f16x8*)&SP[off] = pr;
    }
  };

  // load this thread's xv segment (96 fp16 = rows i in [wv*32,+32) x 3)
  _Float16 xvb[96];
  auto load_xv = [&]() {
#pragma unroll
    for (int u = 0; u < 12; ++u) {
      f16x8 t = *(const f16x8*)&uprow[128 + wv * 96 + u * 8];
#pragma unroll
      for (int z = 0; z < 8; ++z) xvb[u * 8 + z] = t[z];
    }
  };

  // TP for w4: A = SW[e][i] * dot(xv[i], yv)
  auto tp_w4 = [&]() {
    float4 ea = *(const float4*)&edge_attrs[(size_t)(e0 + e_loc) * 4];
#pragma unroll
    for (int cch = 0; cch < 4; ++cch) {
      int ib = nw / 2 + cch * 8;
      int blk = ((ib >> 4) ^ ers) & 7;
      int off = e_loc * 128 + (blk << 4) + (ib & 15);
      f16x8 swv = *(const f16x8*)&SW[off];
      f16x8 outv;
#pragma unroll
      for (int z = 0; z < 8; ++z) {
        int k = cch * 8 + z;
        float d = (float)xvb[k * 3] * ea.y + (float)xvb[k * 3 + 1] * ea.z +
                  (float)xvb[k * 3 + 2] * ea.w;
        outv[z] = (_Float16)((float)swv[z] * d);
      }
      *(f16x8*)&SP[off] = outv;
    }
  };

  // TP for w3 plane c: A = SW[e][i] * xv[i][c]
  auto tp_w3 = [&](int c) {
#pragma unroll
    for (int cch = 0; cch < 4; ++cch) {
      int ib = nw / 2 + cch * 8;
      int blk = ((ib >> 4) ^ ers) & 7;
      int off = e_loc * 128 + (blk << 4) + (ib & 15);
      f16x8 swv = *(const f16x8*)&SW[off];
      f16x8 outv;
#pragma unroll
      for (int z = 0; z < 8; ++z) {
        int k = cch * 8 + z;
        outv[z] = swv[z] * xvb[k * 3 + c];
      }
      *(f16x8*)&SP[off] = outv;
    }
  };

  f32x4 P1[4][2], P4[4][2], P2[4][2], P3[4][2];

  // ---- quarter w1 (tpw cols 0-127): A1 = w1 (x) xs -> P1 = A1 @ WL0a
  qgemm(0);
  sw_write();                 // HB free: layer-2 readers passed the last sync
  __syncthreads();
  tp_xs();
  __syncthreads();
  fold(WL0h, 0, P1);

  // ---- quarter w4 (cols 384-511): A4 = w4 (x) dot(xv,yv) -> P4 = A4 @ WL0b
  qgemm(384);
  __syncthreads();            // all TP reads of SW(w1) complete
  sw_write();
  load_xv();
  __syncthreads();
  tp_w4();
  __syncthreads();
  fold(WL0h, 1, P4);

  // scalar part: MIDs[:, j] = y0*P1 + P4/sqrt(3)
#pragma unroll
  for (int rt = 0; rt < 4; ++rt)
#pragma unroll
    for (int r4 = 0; r4 < 4; ++r4) {
      int row = rt * 16 + g * 4 + r4;
      float4 ea = *(const float4*)&edge_attrs[(size_t)(e0 + row) * 4];
#pragma unroll
      for (int ct = 0; ct < 2; ++ct) {
        int j = wv * 32 + ct * 16 + m;
        float v = ea.x * P1[rt][ct][r4] + INV_SQRT3F * P4[rt][ct][r4];
        MIDs[(size_t)(e0 + row) * 512 + j] = (_Float16)v;
      }
    }

  // ---- quarter w2 (cols 128-255): A2 = w2 (x) xs -> P2 = A2 @ WL1a
  qgemm(128);
  __syncthreads();
  sw_write();
  __syncthreads();
  tp_xs();
  __syncthreads();
  fold(WL1h, 0, P2);

  // ---- quarter w3 (cols 256-383): per plane c: A3c = w3 (x) xv[:,c] -> P3 = A3c @ WL1b
  qgemm(256);
  __syncthreads();
  sw_write();
  __syncthreads();
#pragma unroll
  for (int c = 0; c < 3; ++c) {
    tp_w3(c);
    __syncthreads();
    fold(WL1h, 1, P3);
    // plane c: MIDs[:, 128 + c*128 + j] = yv[c]*P2 + y0*P3
#pragma unroll
    for (int rt = 0; rt < 4; ++rt)
#pragma unroll
      for (int r4 = 0; r4 < 4; ++r4) {
        int row = rt * 16 + g * 4 + r4;
        float4 ea = *(const float4*)&edge_attrs[(size_t)(e0 + row) * 4];
        float yvc = (c == 0) ? ea.y : (c == 1) ? ea.z : ea.w;
#pragma unroll
        for (int ct = 0; ct < 2; ++ct) {
          int j = wv * 32 + ct * 16 + m;
          float v = yvc * P2[rt][ct][r4] + ea.x * P3[rt][ct][r4];
          MIDs[(size_t)(e0 + row) * 512 + 128 + c * 128 + j] = (_Float16)v;
        }
      }
    __syncthreads();          // before next plane overwrites SP
  }
}

// ---------------------------------------------------------------------------
// Gather: one block per node, sum per-edge message contributions (fp32 acc),
// write interleaved output: x<128 -> msg_s[x]; else c=(x-128)>>7, j=(x-128)&127
// ---------------------------------------------------------------------------
__global__ __launch_bounds__(256) void gather_msg(
    const _Float16* __restrict__ MIDs, const int* __restrict__ OFF,
    const int* __restrict__ EIDX, float* __restrict__ out) {
  const int n = blockIdx.x;
  const int t = threadIdx.x;
  const int beg = OFF[n], end = OFF[n + 1];
  float a0 = 0.f, a1 = 0.f;
  for (int k = beg; k < end; ++k) {
    int e = EIDX[k];
    f16x2 v = *(const f16x2*)&MIDs[(size_t)e * 512 + t * 2];
    a0 += (float)v[0];
    a1 += (float)v[1];
  }
#pragma unroll
  for (int u = 0; u < 2; ++u) {
    int x = t * 2 + u;
    float a = u ? a1 : a0;
    int dst;
    if (x < 128) {
      dst = n * 512 + x * 4;
    } else {
      int xm = x - 128;
      int c = xm >> 7, j = xm & 127;
      dst = n * 512 + j * 4 + 1 + c;
    }
    out[dst] = a;
  }
}

// ---------------------------------------------------------------------------
extern "C" void kernel_launch(void* const* d_in, const int* in_sizes, int n_in,
                              void* d_out, int out_size, void* d_ws, size_t ws_size,
                              hipStream_t stream) {
  const float* node_feats = (const float*)d_in[1];
  const float* edge_attrs = (const float*)d_in[2];
  const float* edge_feats = (const float*)d_in[3];
  const int*   edge_index = (const int*)d_in[4];
  const float* W_up0   = (const float*)d_in[5];
  const float* W_up1   = (const float*)d_in[6];
  const float* W_down  = (const float*)d_in[7];
  const float* Wm0     = (const float*)d_in[8];
  const float* Wm1     = (const float*)d_in[9];
  const float* Wm2     = (const float*)d_in[10];
  const float* Wm3     = (const float*)d_in[11];
  const float* W_lin0  = (const float*)d_in[12];
  const float* W_lin1  = (const float*)d_in[13];
  const float* W_skip0 = (const float*)d_in[14];
  const float* W_skip1 = (const float*)d_in[15];
  float* out = (float*)d_out;

  char* ws = (char*)d_ws;
  size_t off = 0;
  auto alloc = [&](size_t bytes) {
    void* p = ws + off;
    off = (off + bytes + 255) & ~(size_t)255;
    return p;
  };
  _Float16* UPH   = (_Float16*)alloc((size_t)NN * 512 * 2);
  _Float16* DOWNH = (_Float16*)alloc((size_t)NN * 64 * 2);
  _Float16* W0h   = (_Float16*)alloc(160 * 256 * 2);
  _Float16* W1h   = (_Float16*)alloc(256 * 256 * 2);
  _Float16* W2h   = (_Float16*)alloc(256 * 256 * 2);
  _Float16* W3h   = (_Float16*)alloc(256 * 512 * 2);
  _Float16* WL0h  = (_Float16*)alloc(256 * 128 * 2);
  _Float16* WL1h  = (_Float16*)alloc(256 * 128 * 2);
  int*      CNT   = (int*)alloc((size_t)NN * 4);
  int*      OFF   = (int*)alloc((size_t)(NN + 1) * 4);
  int*      CUR   = (int*)alloc((size_t)NN * 4);
  int*      EIDX  = (int*)alloc((size_t)NE * 4);
  _Float16* MIDs  = (_Float16*)alloc((size_t)NE * 512 * 2);

  hipMemsetAsync(CNT, 0, (size_t)NN * 4, stream);

  // scales folded into fp16 weights: 1/sqrt(136) layer0, 1/16 layers 1..3,
  // 1/(sqrt(256)*16)=1/256 for W_lin (includes AVG_NEIGH)
  wconv<<<160, 256, 0, stream>>>(Wm0, W0h, 136, 160, 256, 1.0f / sqrtf(136.0f));
  wconv<<<256, 256, 0, stream>>>(Wm1, W1h, 256, 256, 256, 0.0625f);
  wconv<<<256, 256, 0, stream>>>(Wm2, W2h, 256, 256, 256, 0.0625f);
  wconv<<<512, 256, 0, stream>>>(Wm3, W3h, 256, 256, 512, 0.0625f);
  wconv<<<128, 256, 0, stream>>>(W_lin0, WL0h, 256, 256, 128, 1.0f / 256.0f);
  wconv<<<128, 256, 0, stream>>>(W_lin1, WL1h, 256, 256, 128, 1.0f / 256.0f);

  node_pre<<<dim3(625, 5), 256, 0, stream>>>(node_feats, W_up0, W_up1, W_skip0,
                                             W_skip1, W_down, UPH, DOWNH,
                                             out + (size_t)NN * 512);
  k_count<<<625, 256, 0, stream>>>(edge_index, CNT);
  k_scan<<<1, 1024, 0, stream>>>(CNT, OFF, CUR);
  k_fill<<<625, 256, 0, stream>>>(edge_index, CUR, EIDX);

  edge_mlp<<<2500, 256, 0, stream>>>(edge_attrs, edge_feats, edge_index, DOWNH,
                                     UPH, W0h, W1h, W2h, W3h, WL0h, WL1h, MIDs);
  gather_msg<<<NN, 256, 0, stream>>>(MIDs, OFF, EIDX, out);
}

// Round 4
// 565.417 us; speedup vs baseline: 2.9674x; 1.1746x over previous
//
#include <hip/hip_runtime.h>
#include <cmath>

#define NN 10000
#define NE 160000
#define INV_SQRT_C 0.08838834764831845f   // 1/sqrt(128)
#define INV_SQRT3F 0.5773502691896258f

typedef _Float16 f16x8 __attribute__((ext_vector_type(8)));
typedef _Float16 f16x4 __attribute__((ext_vector_type(4)));
typedef _Float16 f16x2 __attribute__((ext_vector_type(2)));
typedef float    f32x4 __attribute__((ext_vector_type(4)));

__device__ __forceinline__ float silu_f(float x) {
  return x / (1.f + __expf(-x));
}

// ---------------------------------------------------------------------------
// Weight conversion fp32 -> fp16, swizzled for MFMA B-fragments, with
// column permutation so lane-adjacent output slots are memory-adjacent:
//   storage col n (within chunk of P): slot sub = ct*16+m holds logical
//   column m*(P/16)+ct. Thus MFMA C/D written at "position" = logical col.
//   dst[(kb*N + n)*32 + kk] = src[k*N + n_l] * scale  (0 if k >= Korig)
// ---------------------------------------------------------------------------
__global__ void wconv(const float* __restrict__ src, _Float16* __restrict__ dst,
                      int Korig, int Kpad, int N, float scale, int P) {
  int total = Kpad * N;
  for (int t = blockIdx.x * blockDim.x + threadIdx.x; t < total;
       t += gridDim.x * blockDim.x) {
    int n = t % N;
    int k = t / N;
    int kb = k >> 5, kk = k & 31;
    int sub = n & (P - 1);
    int n_l = (n & ~(P - 1)) | ((sub & 15) * (P >> 4) + (sub >> 4));
    float v = (k < Korig) ? src[(size_t)k * N + n_l] * scale : 0.f;
    dst[((size_t)(kb * N + n) << 5) + kk] = (_Float16)v;
  }
}

// ---------------------------------------------------------------------------
// Node pre-pass (unchanged, verified): up_s/up_v -> UPH (fp16, logical
// layout [s(128) | v(384 interleaved)]), sc -> out upper half, down -> DOWNH.
// ---------------------------------------------------------------------------
__global__ __launch_bounds__(256) void node_pre(
    const float* __restrict__ feats,
    const float* __restrict__ W_up0, const float* __restrict__ W_up1,
    const float* __restrict__ W_skip0, const float* __restrict__ W_skip1,
    const float* __restrict__ W_down,
    _Float16* __restrict__ UPH, _Float16* __restrict__ DOWNH,
    float* __restrict__ out_sc) {
  __shared__ float ls[16 * 384];
  const int y = blockIdx.y;
  const int n0 = blockIdx.x * 16;
  const int t = threadIdx.x;

  if (y == 0 || y == 2 || y == 4) {
    for (int f = t; f < 16 * 128; f += 256) {
      int r = f >> 7, c = f & 127;
      ls[r * 128 + c] = feats[(size_t)(n0 + r) * 512 + c];
    }
    __syncthreads();
    if (y == 4) {
      int j = t & 63, g = t >> 6;
      float acc[4] = {0.f, 0.f, 0.f, 0.f};
      for (int i = 0; i < 128; ++i) {
        float w = W_down[(size_t)i * 64 + j];
#pragma unroll
        for (int r = 0; r < 4; ++r) acc[r] += ls[(g * 4 + r) * 128 + i] * w;
      }
#pragma unroll
      for (int r = 0; r < 4; ++r)
        DOWNH[(size_t)(n0 + g * 4 + r) * 64 + j] = (_Float16)(acc[r] * INV_SQRT_C);
    } else {
      const float* W = (y == 0) ? W_up0 : W_skip0;
      int j = t & 127, g = t >> 7;
      float acc[8] = {0.f, 0.f, 0.f, 0.f, 0.f, 0.f, 0.f, 0.f};
      for (int i = 0; i < 128; ++i) {
        float w = W[(size_t)i * 128 + j];
#pragma unroll
        for (int r = 0; r < 8; ++r) acc[r] += ls[(g * 8 + r) * 128 + i] * w;
      }
#pragma unroll
      for (int r = 0; r < 8; ++r) {
        int n = n0 + g * 8 + r;
        float v = acc[r] * INV_SQRT_C;
        if (y == 0) UPH[(size_t)n * 512 + j] = (_Float16)v;
        else        out_sc[(size_t)n * 512 + j] = v;
      }
    }
  } else {
    for (int f = t; f < 16 * 384; f += 256) {
      int r = f / 384, c = f % 384;
      ls[r * 384 + c] = feats[(size_t)(n0 + r) * 512 + 128 + c];
    }
    __syncthreads();
    const float* W = (y == 1) ? W_up1 : W_skip1;
    int j = t & 127, g = t >> 7;
    float acc[8][3];
#pragma unroll
    for (int r = 0; r < 8; ++r)
#pragma unroll
      for (int c = 0; c < 3; ++c) acc[r][c] = 0.f;
    for (int i = 0; i < 128; ++i) {
      float w = W[(size_t)i * 128 + j];
#pragma unroll
      for (int r = 0; r < 8; ++r) {
#pragma unroll
        for (int c = 0; c < 3; ++c)
          acc[r][c] += ls[(g * 8 + r) * 384 + i * 3 + c] * w;
      }
    }
#pragma unroll
    for (int r = 0; r < 8; ++r) {
      int n = n0 + g * 8 + r;
#pragma unroll
      for (int c = 0; c < 3; ++c) {
        float v = acc[r][c] * INV_SQRT_C;
        if (y == 1) UPH[(size_t)n * 512 + 128 + j * 3 + c] = (_Float16)v;
        else        out_sc[(size_t)n * 512 + 128 + j * 3 + c] = v;
      }
    }
  }
}

// ---------------------------------------------------------------------------
// CSR build: count per-receiver degree, exclusive scan, fill edge list.
// ---------------------------------------------------------------------------
__global__ void k_count(const int* __restrict__ edge_index, int* __restrict__ CNT) {
  int e = blockIdx.x * blockDim.x + threadIdx.x;
  if (e < NE) atomicAdd(&CNT[edge_index[e * 2 + 1]], 1);
}

__global__ __launch_bounds__(1024) void k_scan(const int* __restrict__ CNT,
                                               int* __restrict__ OFF,
                                               int* __restrict__ CUR) {
  __shared__ int ts[1024];
  const int t = threadIdx.x;
  const int base = t * 10;
  int loc[10];
  int s = 0;
#pragma unroll
  for (int i = 0; i < 10; ++i) {
    int idx = base + i;
    int v = (idx < NN) ? CNT[idx] : 0;
    loc[i] = s;
    s += v;
  }
  ts[t] = s;
  __syncthreads();
  for (int off = 1; off < 1024; off <<= 1) {
    int v = (t >= off) ? ts[t - off] : 0;
    __syncthreads();
    ts[t] += v;
    __syncthreads();
  }
  int tp = (t > 0) ? ts[t - 1] : 0;
#pragma unroll
  for (int i = 0; i < 10; ++i) {
    int idx = base + i;
    if (idx < NN) {
      OFF[idx] = tp + loc[i];
      CUR[idx] = tp + loc[i];
    }
  }
  if (t == 1023) OFF[NN] = ts[1023];
}

__global__ void k_fill(const int* __restrict__ edge_index, int* __restrict__ CUR,
                       int* __restrict__ EIDX) {
  int e = blockIdx.x * blockDim.x + threadIdx.x;
  if (e < NE) {
    int r = edge_index[e * 2 + 1];
    int pos = atomicAdd(&CUR[r], 1);
    EIDX[pos] = e;
  }
}

// ---------------------------------------------------------------------------
// Fused edge kernel. 64 edges/block, 256 threads (4 waves).
// With column-permuted B (wconv P-perm), MFMA outputs land at memory-adjacent
// positions -> packed f16x4 layer stores, f16x2 SW stores, f16x2 MIDs stores.
// h positions == logical feature indices (K side needs no permutation).
// LDS swizzle (layers, 256-col): addr = row*256 + ((blk ^ (row&15))<<4)+off
// Epilogue swizzle (128-col): blk ^= (row ^ row>>3)&7.
// Barriers only where SP crosses waves (fold reads all columns).
// ---------------------------------------------------------------------------
__device__ __forceinline__ void mlp_layer_256(
    const _Float16* In, _Float16* Out, const _Float16* __restrict__ Wz,
    int m, int g, int wv) {
  f32x4 acc[4][4];
  f32x4 zero4 = {0.f, 0.f, 0.f, 0.f};
#pragma unroll
  for (int rt = 0; rt < 4; ++rt)
#pragma unroll
    for (int ct = 0; ct < 4; ++ct) acc[rt][ct] = zero4;

#pragma unroll
  for (int kb = 0; kb < 8; ++kb) {
    f16x8 a[4], b[4];
#pragma unroll
    for (int rt = 0; rt < 4; ++rt) {
      int row = rt * 16 + m;
      a[rt] = *(const f16x8*)&In[row * 256 + (((kb * 2 + (g >> 1)) ^ m) << 4) + (g & 1) * 8];
    }
#pragma unroll
    for (int ct = 0; ct < 4; ++ct)
      b[ct] = *(const f16x8*)&Wz[((size_t)(kb * 256 + wv * 64 + ct * 16 + m) << 5) + g * 8];
#pragma unroll
    for (int rt = 0; rt < 4; ++rt)
#pragma unroll
      for (int ct = 0; ct < 4; ++ct)
        acc[rt][ct] = __builtin_amdgcn_mfma_f32_16x16x32_f16(a[rt], b[ct], acc[rt][ct], 0, 0, 0);
  }
  // packed store: acc[ct] holds logical col wv*64 + m*4 + ct (B is P64-permuted)
#pragma unroll
  for (int rt = 0; rt < 4; ++rt)
#pragma unroll
    for (int q = 0; q < 4; ++q) {
      int row = rt * 16 + g * 4 + q;
      f16x4 pk;
#pragma unroll
      for (int ct = 0; ct < 4; ++ct) pk[ct] = (_Float16)silu_f(acc[rt][ct][q]);
      int blk = (wv * 4 + (m >> 2)) ^ (row & 15);
      *(f16x4*)&Out[row * 256 + (blk << 4) + (m & 3) * 4] = pk;
    }
}

__global__ __launch_bounds__(256, 2) void edge_mlp(
    const float* __restrict__ edge_attrs,
    const float* __restrict__ edge_feats,
    const int* __restrict__ edge_index,
    const _Float16* __restrict__ DOWNH,
    const _Float16* __restrict__ UPH,
    const _Float16* __restrict__ W0h, const _Float16* __restrict__ W1h,
    const _Float16* __restrict__ W2h, const _Float16* __restrict__ W3h,
    const _Float16* __restrict__ WL0h, const _Float16* __restrict__ WL1h,
    _Float16* __restrict__ MIDs) {
  __shared__ _Float16 HA[64 * 256];
  __shared__ _Float16 HB[64 * 256];

  const int tid = threadIdx.x;
  const int lane = tid & 63;
  const int wv = tid >> 6;
  const int m = lane & 15;
  const int g = lane >> 4;
  const int e0 = blockIdx.x * 64;
  const int nw = wv * 64;

  int snd_r[4], rcv_r[4];
#pragma unroll
  for (int rt = 0; rt < 4; ++rt) {
    int2 sr = *(const int2*)&edge_index[(size_t)(e0 + rt * 16 + m) * 2];
    snd_r[rt] = sr.x;
    rcv_r[rt] = sr.y;
  }

  f32x4 zero4 = {0.f, 0.f, 0.f, 0.f};
  f16x8 zf = {0, 0, 0, 0, 0, 0, 0, 0};

  // ---------------- layer 0: aug(136, padded 160) -> h1 (HA)
  {
    f32x4 acc[4][4];
#pragma unroll
    for (int rt = 0; rt < 4; ++rt)
#pragma unroll
      for (int ct = 0; ct < 4; ++ct) acc[rt][ct] = zero4;

#pragma unroll
    for (int kb = 0; kb < 5; ++kb) {
      const int k0 = kb * 32 + g * 8;
      f16x8 a[4], b[4];
#pragma unroll
      for (int rt = 0; rt < 4; ++rt) {
        if (k0 == 0) {
          const float* ef = &edge_feats[(size_t)(e0 + rt * 16 + m) * 8];
          float4 f0 = *(const float4*)ef;
          float4 f1 = *(const float4*)(ef + 4);
          f16x8 av;
          av[0] = (_Float16)f0.x; av[1] = (_Float16)f0.y;
          av[2] = (_Float16)f0.z; av[3] = (_Float16)f0.w;
          av[4] = (_Float16)f1.x; av[5] = (_Float16)f1.y;
          av[6] = (_Float16)f1.z; av[7] = (_Float16)f1.w;
          a[rt] = av;
        } else if (k0 < 72) {
          a[rt] = *(const f16x8*)&DOWNH[(size_t)snd_r[rt] * 64 + (k0 - 8)];
        } else if (k0 < 136) {
          a[rt] = *(const f16x8*)&DOWNH[(size_t)rcv_r[rt] * 64 + (k0 - 72)];
        } else {
          a[rt] = zf;
        }
      }
#pragma unroll
      for (int ct = 0; ct < 4; ++ct)
        b[ct] = *(const f16x8*)&W0h[((size_t)(kb * 256 + nw + ct * 16 + m) << 5) + g * 8];
#pragma unroll
      for (int rt = 0; rt < 4; ++rt)
#pragma unroll
        for (int ct = 0; ct < 4; ++ct)
          acc[rt][ct] = __builtin_amdgcn_mfma_f32_16x16x32_f16(a[rt], b[ct], acc[rt][ct], 0, 0, 0);
    }
#pragma unroll
    for (int rt = 0; rt < 4; ++rt)
#pragma unroll
      for (int q = 0; q < 4; ++q) {
        int row = rt * 16 + g * 4 + q;
        f16x4 pk;
#pragma unroll
        for (int ct = 0; ct < 4; ++ct) pk[ct] = (_Float16)silu_f(acc[rt][ct][q]);
        int blk = (wv * 4 + (m >> 2)) ^ (row & 15);
        *(f16x4*)&HA[row * 256 + (blk << 4) + (m & 3) * 4] = pk;
      }
  }
  __syncthreads();

  mlp_layer_256(HA, HB, W1h, m, g, wv);   // layer 1: h1 -> h2
  __syncthreads();
  mlp_layer_256(HB, HA, W2h, m, g, wv);   // layer 2: h2 -> h3 (HA, stays live)
  __syncthreads();

  // ================= epilogue =================
  _Float16* SW = HB;             // 64 x 128 fp16 (16 KB), tpw quarter
  _Float16* SP = HB + 64 * 128;  // 64 x 128 fp16 (16 KB), TP'd A-matrix

  const int e_loc = lane;                       // consumer edge (per wave)
  const int ers = (e_loc ^ (e_loc >> 3)) & 7;   // row swizzle key for e_loc
  const int snd_e = edge_index[(size_t)(e0 + e_loc) * 2];
  const _Float16* uprow = &UPH[(size_t)snd_e * 512];

  f32x4 accq[4][2];

  // quarter GEMM: h3(HA) @ Wm3[:, qbase..qbase+128) -> accq
  auto qgemm = [&](int qbase) {
#pragma unroll
    for (int rt = 0; rt < 4; ++rt)
#pragma unroll
      for (int ct = 0; ct < 2; ++ct) accq[rt][ct] = zero4;
#pragma unroll
    for (int kb = 0; kb < 8; ++kb) {
      f16x8 a[4], b[2];
#pragma unroll
      for (int rt = 0; rt < 4; ++rt) {
        int row = rt * 16 + m;
        a[rt] = *(const f16x8*)&HA[row * 256 + (((kb * 2 + (g >> 1)) ^ m) << 4) + (g & 1) * 8];
      }
#pragma unroll
      for (int ct = 0; ct < 2; ++ct)
        b[ct] = *(const f16x8*)&W3h[((size_t)(kb * 512 + qbase + wv * 32 + ct * 16 + m) << 5) + g * 8];
#pragma unroll
      for (int rt = 0; rt < 4; ++rt)
#pragma unroll
        for (int ct = 0; ct < 2; ++ct)
          accq[rt][ct] = __builtin_amdgcn_mfma_f32_16x16x32_f16(a[rt], b[ct], accq[rt][ct], 0, 0, 0);
    }
  };

  // accq[ct] holds logical col wv*32 + m*2 + ct (W3h is P32-permuted):
  // packed f16x2 transpose into SW (positions are logical cols)
  auto sw_write = [&]() {
#pragma unroll
    for (int rt = 0; rt < 4; ++rt)
#pragma unroll
      for (int r4 = 0; r4 < 4; ++r4) {
        int row = rt * 16 + g * 4 + r4;
        int rs = (row ^ (row >> 3)) & 7;
        f16x2 pk;
        pk[0] = (_Float16)accq[rt][0][r4];
        pk[1] = (_Float16)accq[rt][1][r4];
        int blk = ((wv * 2 + (m >> 3)) ^ rs) & 7;
        *(f16x2*)&SW[row * 128 + (blk << 4) + (m & 7) * 2] = pk;
      }
  };

  // fold GEMM: SP[64x128] @ WLh[qpart] -> P ; P[ct] = logical col wv*32+m*2+ct
  auto fold = [&](const _Float16* __restrict__ WLh, int qpart, f32x4 (&P)[4][2]) {
#pragma unroll
    for (int rt = 0; rt < 4; ++rt)
#pragma unroll
      for (int ct = 0; ct < 2; ++ct) P[rt][ct] = zero4;
#pragma unroll
    for (int kb = 0; kb < 4; ++kb) {
      f16x8 a[4], b[2];
#pragma unroll
      for (int rt = 0; rt < 4; ++rt) {
        int row = rt * 16 + m;
        int rs = (row ^ (row >> 3)) & 7;
        a[rt] = *(const f16x8*)&SP[row * 128 + ((((kb * 2 + (g >> 1)) ^ rs) & 7) << 4) + (g & 1) * 8];
      }
#pragma unroll
      for (int ct = 0; ct < 2; ++ct)
        b[ct] = *(const f16x8*)&WLh[((size_t)((qpart * 4 + kb) * 128 + wv * 32 + ct * 16 + m) << 5) + g * 8];
#pragma unroll
      for (int rt = 0; rt < 4; ++rt)
#pragma unroll
        for (int ct = 0; ct < 2; ++ct)
          P[rt][ct] = __builtin_amdgcn_mfma_f32_16x16x32_f16(a[rt], b[ct], P[rt][ct], 0, 0, 0);
    }
  };

  // TP: SP[e][i] = SW[e][i] * xs[i], i in [wv*32, wv*32+32) — wave-private cols
  auto tp_xs = [&]() {
#pragma unroll
    for (int cch = 0; cch < 4; ++cch) {
      int ib = nw / 2 + cch * 8;
      int blk = ((ib >> 4) ^ ers) & 7;
      int off = e_loc * 128 + (blk << 4) + (ib & 15);
      f16x8 swv = *(const f16x8*)&SW[off];
      f16x8 upv = *(const f16x8*)&uprow[ib];
      f16x8 pr = swv * upv;
      *(f16x8*)&SP[off] = pr;
    }
  };

  _Float16 xvb[96];
  auto load_xv = [&]() {
#pragma unroll
    for (int u = 0; u < 12; ++u) {
      f16x8 t = *(const f16x8*)&uprow[128 + wv * 96 + u * 8];
#pragma unroll
      for (int z = 0; z < 8; ++z) xvb[u * 8 + z] = t[z];
    }
  };

  auto tp_w4 = [&]() {
    float4 ea = *(const float4*)&edge_attrs[(size_t)(e0 + e_loc) * 4];
#pragma unroll
    for (int cch = 0; cch < 4; ++cch) {
      int ib = nw / 2 + cch * 8;
      int blk = ((ib >> 4) ^ ers) & 7;
      int off = e_loc * 128 + (blk << 4) + (ib & 15);
      f16x8 swv = *(const f16x8*)&SW[off];
      f16x8 outv;
#pragma unroll
      for (int z = 0; z < 8; ++z) {
        int k = cch * 8 + z;
        float d = (float)xvb[k * 3] * ea.y + (float)xvb[k * 3 + 1] * ea.z +
                  (float)xvb[k * 3 + 2] * ea.w;
        outv[z] = (_Float16)((float)swv[z] * d);
      }
      *(f16x8*)&SP[off] = outv;
    }
  };

  auto tp_w3 = [&](int c) {
#pragma unroll
    for (int cch = 0; cch < 4; ++cch) {
      int ib = nw / 2 + cch * 8;
      int blk = ((ib >> 4) ^ ers) & 7;
      int off = e_loc * 128 + (blk << 4) + (ib & 15);
      f16x8 swv = *(const f16x8*)&SW[off];
      f16x8 outv;
#pragma unroll
      for (int z = 0; z < 8; ++z) {
        int k = cch * 8 + z;
        outv[z] = swv[z] * xvb[k * 3 + c];
      }
      *(f16x8*)&SP[off] = outv;
    }
  };

  f32x4 P1[4][2], P4[4][2], P2[4][2], P3[4][2];

  // ---- q1 (w1, tpw cols 0-127): A1 = w1 (x) xs ; P1 = A1 @ WL0a
  qgemm(0);
  sw_write();                 // HB free (post-layer2 sync); wave-private cols
  tp_xs();                    // reads own SW cols (in-order DS per wave)
  __syncthreads();            // SP complete (all waves)
  fold(WL0h, 0, P1);

  // ---- q4 (w4, cols 384-511): A4 = w4 (x) dot(xv,yv) ; P4 = A4 @ WL0b
  qgemm(384);
  sw_write();                 // own cols; prior own-wave TP reads done
  load_xv();
  __syncthreads();            // fold(P1) done reading SP everywhere
  tp_w4();
  __syncthreads();
  fold(WL0h, 1, P4);

  // scalar part: MIDs[:, j] = y0*P1 + P4/sqrt(3)   (packed f16x2)
#pragma unroll
  for (int rt = 0; rt < 4; ++rt)
#pragma unroll
    for (int r4 = 0; r4 < 4; ++r4) {
      int row = rt * 16 + g * 4 + r4;
      float4 ea = *(const float4*)&edge_attrs[(size_t)(e0 + row) * 4];
      f16x2 pk;
      pk[0] = (_Float16)(ea.x * P1[rt][0][r4] + INV_SQRT3F * P4[rt][0][r4]);
      pk[1] = (_Float16)(ea.x * P1[rt][1][r4] + INV_SQRT3F * P4[rt][1][r4]);
      *(f16x2*)&MIDs[(size_t)(e0 + row) * 512 + wv * 32 + m * 2] = pk;
    }

  // ---- q2 (w2, cols 128-255): A2 = w2 (x) xs ; P2 = A2 @ WL1a
  qgemm(128);
  sw_write();
  __syncthreads();            // fold(P4) done reading SP
  tp_xs();
  __syncthreads();
  fold(WL1h, 0, P2);

  // ---- q3 (w3, cols 256-383): per plane c: A3c = w3 (x) xv[:,c] ; P3 = A3c @ WL1b
  qgemm(256);
  sw_write();
#pragma unroll
  for (int c = 0; c < 3; ++c) {
    __syncthreads();          // previous fold done reading SP
    tp_w3(c);
    __syncthreads();
    fold(WL1h, 1, P3);
    // plane c: MIDs[:, 128 + c*128 + j] = yv[c]*P2 + y0*P3  (packed)
#pragma unroll
    for (int rt = 0; rt < 4; ++rt)
#pragma unroll
      for (int r4 = 0; r4 < 4; ++r4) {
        int row = rt * 16 + g * 4 + r4;
        float4 ea = *(const float4*)&edge_attrs[(size_t)(e0 + row) * 4];
        float yvc = (c == 0) ? ea.y : (c == 1) ? ea.z : ea.w;
        f16x2 pk;
        pk[0] = (_Float16)(yvc * P2[rt][0][r4] + ea.x * P3[rt][0][r4]);
        pk[1] = (_Float16)(yvc * P2[rt][1][r4] + ea.x * P3[rt][1][r4]);
        *(f16x2*)&MIDs[(size_t)(e0 + row) * 512 + 128 + c * 128 + wv * 32 + m * 2] = pk;
      }
  }
}

// ---------------------------------------------------------------------------
// Gather: one block per node. Stage edge ids in LDS, 4-way unrolled
// independent loads (breaks the EIDX->MIDs dependency chain), fp32 acc.
// ---------------------------------------------------------------------------
__global__ __launch_bounds__(256) void gather_msg(
    const _Float16* __restrict__ MIDs, const int* __restrict__ OFF,
    const int* __restrict__ EIDX, float* __restrict__ out) {
  __shared__ int eb[256];
  const int n = blockIdx.x;
  const int t = threadIdx.x;
  const int beg = OFF[n], end = OFF[n + 1];
  float a0 = 0.f, a1 = 0.f;
  for (int base = beg; base < end; base += 256) {
    int cnt = min(256, end - base);
    __syncthreads();
    if (t < cnt) eb[t] = EIDX[base + t];
    __syncthreads();
    int k = 0;
    for (; k + 4 <= cnt; k += 4) {
      int e0_ = eb[k], e1_ = eb[k + 1], e2_ = eb[k + 2], e3_ = eb[k + 3];
      f16x2 v0 = *(const f16x2*)&MIDs[(size_t)e0_ * 512 + t * 2];
      f16x2 v1 = *(const f16x2*)&MIDs[(size_t)e1_ * 512 + t * 2];
      f16x2 v2 = *(const f16x2*)&MIDs[(size_t)e2_ * 512 + t * 2];
      f16x2 v3 = *(const f16x2*)&MIDs[(size_t)e3_ * 512 + t * 2];
      a0 += (float)v0[0] + (float)v1[0] + (float)v2[0] + (float)v3[0];
      a1 += (float)v0[1] + (float)v1[1] + (float)v2[1] + (float)v3[1];
    }
    for (; k < cnt; ++k) {
      f16x2 v = *(const f16x2*)&MIDs[(size_t)eb[k] * 512 + t * 2];
      a0 += (float)v[0];
      a1 += (float)v[1];
    }
  }
#pragma unroll
  for (int u = 0; u < 2; ++u) {
    int x = t * 2 + u;
    float a = u ? a1 : a0;
    int dst;
    if (x < 128) {
      dst = n * 512 + x * 4;
    } else {
      int xm = x - 128;
      int c = xm >> 7, j = xm & 127;
      dst = n * 512 + j * 4 + 1 + c;
    }
    out[dst] = a;
  }
}

// ---------------------------------------------------------------------------
extern "C" void kernel_launch(void* const* d_in, const int* in_sizes, int n_in,
                              void* d_out, int out_size, void* d_ws, size_t ws_size,
                              hipStream_t stream) {
  const float* node_feats = (const float*)d_in[1];
  const float* edge_attrs = (const float*)d_in[2];
  const float* edge_feats = (const float*)d_in[3];
  const int*   edge_index = (const int*)d_in[4];
  const float* W_up0   = (const float*)d_in[5];
  const float* W_up1   = (const float*)d_in[6];
  const float* W_down  = (const float*)d_in[7];
  const float* Wm0     = (const float*)d_in[8];
  const float* Wm1     = (const float*)d_in[9];
  const float* Wm2     = (const float*)d_in[10];
  const float* Wm3     = (const float*)d_in[11];
  const float* W_lin0  = (const float*)d_in[12];
  const float* W_lin1  = (const float*)d_in[13];
  const float* W_skip0 = (const float*)d_in[14];
  const float* W_skip1 = (const float*)d_in[15];
  float* out = (float*)d_out;

  char* ws = (char*)d_ws;
  size_t off = 0;
  auto alloc = [&](size_t bytes) {
    void* p = ws + off;
    off = (off + bytes + 255) & ~(size_t)255;
    return p;
  };
  _Float16* UPH   = (_Float16*)alloc((size_t)NN * 512 * 2);
  _Float16* DOWNH = (_Float16*)alloc((size_t)NN * 64 * 2);
  _Float16* W0h   = (_Float16*)alloc(160 * 256 * 2);
  _Float16* W1h   = (_Float16*)alloc(256 * 256 * 2);
  _Float16* W2h   = (_Float16*)alloc(256 * 256 * 2);
  _Float16* W3h   = (_Float16*)alloc(256 * 512 * 2);
  _Float16* WL0h  = (_Float16*)alloc(256 * 128 * 2);
  _Float16* WL1h  = (_Float16*)alloc(256 * 128 * 2);
  int*      CNT   = (int*)alloc((size_t)NN * 4);
  int*      OFF   = (int*)alloc((size_t)(NN + 1) * 4);
  int*      CUR   = (int*)alloc((size_t)NN * 4);
  int*      EIDX  = (int*)alloc((size_t)NE * 4);
  _Float16* MIDs  = (_Float16*)alloc((size_t)NE * 512 * 2);

  hipMemsetAsync(CNT, 0, (size_t)NN * 4, stream);

  // scales folded into fp16 weights: 1/sqrt(136) layer0, 1/16 layers 1..3,
  // 1/256 for W_lin (includes sqrt(2C) and AVG_NEIGH)
  wconv<<<160, 256, 0, stream>>>(Wm0, W0h, 136, 160, 256, 1.0f / sqrtf(136.0f), 64);
  wconv<<<256, 256, 0, stream>>>(Wm1, W1h, 256, 256, 256, 0.0625f, 64);
  wconv<<<256, 256, 0, stream>>>(Wm2, W2h, 256, 256, 256, 0.0625f, 64);
  wconv<<<512, 256, 0, stream>>>(Wm3, W3h, 256, 256, 512, 0.0625f, 32);
  wconv<<<128, 256, 0, stream>>>(W_lin0, WL0h, 256, 256, 128, 1.0f / 256.0f, 32);
  wconv<<<128, 256, 0, stream>>>(W_lin1, WL1h, 256, 256, 128, 1.0f / 256.0f, 32);

  node_pre<<<dim3(625, 5), 256, 0, stream>>>(node_feats, W_up0, W_up1, W_skip0,
                                             W_skip1, W_down, UPH, DOWNH,
                                             out + (size_t)NN * 512);
  k_count<<<625, 256, 0, stream>>>(edge_index, CNT);
  k_scan<<<1, 1024, 0, stream>>>(CNT, OFF, CUR);
  k_fill<<<625, 256, 0, stream>>>(edge_index, CUR, EIDX);

  edge_mlp<<<2500, 256, 0, stream>>>(edge_attrs, edge_feats, edge_index, DOWNH,
                                     UPH, W0h, W1h, W2h, W3h, WL0h, WL1h, MIDs);
  gather_msg<<<NN, 256, 0, stream>>>(MIDs, OFF, EIDX, out);
}

// Round 5
// 517.846 us; speedup vs baseline: 3.2400x; 1.0919x over previous
//
#include <hip/hip_runtime.h>
#include <cmath>

#define NN 10000
#define NE 160000
#define INV_SQRT_C 0.08838834764831845f   // 1/sqrt(128)
#define INV_SQRT3F 0.5773502691896258f

typedef _Float16 f16x8 __attribute__((ext_vector_type(8)));
typedef _Float16 f16x4 __attribute__((ext_vector_type(4)));
typedef _Float16 f16x2 __attribute__((ext_vector_type(2)));
typedef float    f32x4 __attribute__((ext_vector_type(4)));

__device__ __forceinline__ float silu_f(float x) {
  return x / (1.f + __expf(-x));
}

// ---------------------------------------------------------------------------
// Weight conversion fp32 -> fp16, B-fragment swizzle + column permutation
// (storage slot ct*16+m within a P-chunk holds logical col m*(P/16)+ct).
// ---------------------------------------------------------------------------
__global__ void wconv(const float* __restrict__ src, _Float16* __restrict__ dst,
                      int Korig, int Kpad, int N, float scale, int P) {
  int total = Kpad * N;
  for (int t = blockIdx.x * blockDim.x + threadIdx.x; t < total;
       t += gridDim.x * blockDim.x) {
    int n = t % N;
    int k = t / N;
    int kb = k >> 5, kk = k & 31;
    int sub = n & (P - 1);
    int n_l = (n & ~(P - 1)) | ((sub & 15) * (P >> 4) + (sub >> 4));
    float v = (k < Korig) ? src[(size_t)k * N + n_l] * scale : 0.f;
    dst[((size_t)(kb * N + n) << 5) + kk] = (_Float16)v;
  }
}

// ---------------------------------------------------------------------------
// Node pre-pass, fused: pass 0 (s-tile): up_s, sc_s, down. pass 1 (v-tile):
// up_v, sc_v. Same arithmetic as the verified 5-pass version.
// ---------------------------------------------------------------------------
__global__ __launch_bounds__(256) void node_pre_s(
    const float* __restrict__ feats,
    const float* __restrict__ W_up0, const float* __restrict__ W_skip0,
    const float* __restrict__ W_down,
    _Float16* __restrict__ UPH, _Float16* __restrict__ DOWNH,
    float* __restrict__ out_sc) {
  __shared__ float ls[16 * 128];
  const int n0 = blockIdx.x * 16;
  const int t = threadIdx.x;
  for (int f = t; f < 16 * 128; f += 256) {
    int r = f >> 7, c = f & 127;
    ls[r * 128 + c] = feats[(size_t)(n0 + r) * 512 + c];
  }
  __syncthreads();
  {
    int j = t & 127, g = t >> 7;  // 8 nodes per group
    float au[8] = {0, 0, 0, 0, 0, 0, 0, 0};
    float ak[8] = {0, 0, 0, 0, 0, 0, 0, 0};
    for (int i = 0; i < 128; ++i) {
      float wu = W_up0[(size_t)i * 128 + j];
      float wk = W_skip0[(size_t)i * 128 + j];
#pragma unroll
      for (int r = 0; r < 8; ++r) {
        float s = ls[(g * 8 + r) * 128 + i];
        au[r] += s * wu;
        ak[r] += s * wk;
      }
    }
#pragma unroll
    for (int r = 0; r < 8; ++r) {
      int n = n0 + g * 8 + r;
      UPH[(size_t)n * 512 + j] = (_Float16)(au[r] * INV_SQRT_C);
      out_sc[(size_t)n * 512 + j] = ak[r] * INV_SQRT_C;
    }
  }
  {
    int j = t & 63, g = t >> 6;  // 4 nodes per group
    float ad[4] = {0, 0, 0, 0};
    for (int i = 0; i < 128; ++i) {
      float wd = W_down[(size_t)i * 64 + j];
#pragma unroll
      for (int r = 0; r < 4; ++r) ad[r] += ls[(g * 4 + r) * 128 + i] * wd;
    }
#pragma unroll
    for (int r = 0; r < 4; ++r)
      DOWNH[(size_t)(n0 + g * 4 + r) * 64 + j] = (_Float16)(ad[r] * INV_SQRT_C);
  }
}

__global__ __launch_bounds__(256) void node_pre_v(
    const float* __restrict__ feats,
    const float* __restrict__ W_up1, const float* __restrict__ W_skip1,
    _Float16* __restrict__ UPH, float* __restrict__ out_sc) {
  __shared__ float ls[16 * 384];
  const int n0 = blockIdx.x * 16;
  const int t = threadIdx.x;
  for (int f = t; f < 16 * 384; f += 256) {
    int r = f / 384, c = f % 384;
    ls[r * 384 + c] = feats[(size_t)(n0 + r) * 512 + 128 + c];
  }
  __syncthreads();
  int j = t & 127, g = t >> 7;
  float au[8][3], ak[8][3];
#pragma unroll
  for (int r = 0; r < 8; ++r)
#pragma unroll
    for (int c = 0; c < 3; ++c) { au[r][c] = 0.f; ak[r][c] = 0.f; }
  for (int i = 0; i < 128; ++i) {
    float wu = W_up1[(size_t)i * 128 + j];
    float wk = W_skip1[(size_t)i * 128 + j];
#pragma unroll
    for (int r = 0; r < 8; ++r) {
#pragma unroll
      for (int c = 0; c < 3; ++c) {
        float v = ls[(g * 8 + r) * 384 + i * 3 + c];
        au[r][c] += v * wu;
        ak[r][c] += v * wk;
      }
    }
  }
#pragma unroll
  for (int r = 0; r < 8; ++r) {
    int n = n0 + g * 8 + r;
#pragma unroll
    for (int c = 0; c < 3; ++c) {
      UPH[(size_t)n * 512 + 128 + j * 3 + c] = (_Float16)(au[r][c] * INV_SQRT_C);
      out_sc[(size_t)n * 512 + 128 + j * 3 + c] = ak[r][c] * INV_SQRT_C;
    }
  }
}

// ---------------------------------------------------------------------------
// CSR build (parameterized by edge_index column: 0=sender, 1=receiver).
// ---------------------------------------------------------------------------
__global__ void k_count(const int* __restrict__ edge_index, int* __restrict__ CNT,
                        int col) {
  int e = blockIdx.x * blockDim.x + threadIdx.x;
  if (e < NE) atomicAdd(&CNT[edge_index[e * 2 + col]], 1);
}

__global__ __launch_bounds__(1024) void k_scan(const int* __restrict__ CNT,
                                               int* __restrict__ OFF,
                                               int* __restrict__ CUR) {
  __shared__ int ts[1024];
  const int t = threadIdx.x;
  const int base = t * 10;
  int loc[10];
  int s = 0;
#pragma unroll
  for (int i = 0; i < 10; ++i) {
    int idx = base + i;
    int v = (idx < NN) ? CNT[idx] : 0;
    loc[i] = s;
    s += v;
  }
  ts[t] = s;
  __syncthreads();
  for (int off = 1; off < 1024; off <<= 1) {
    int v = (t >= off) ? ts[t - off] : 0;
    __syncthreads();
    ts[t] += v;
    __syncthreads();
  }
  int tp = (t > 0) ? ts[t - 1] : 0;
#pragma unroll
  for (int i = 0; i < 10; ++i) {
    int idx = base + i;
    if (idx < NN) {
      OFF[idx] = tp + loc[i];
      CUR[idx] = tp + loc[i];
    }
  }
  if (t == 1023) OFF[NN] = ts[1023];
}

__global__ void k_fill(const int* __restrict__ edge_index, int* __restrict__ CUR,
                       int* __restrict__ IDX, int col) {
  int e = blockIdx.x * blockDim.x + threadIdx.x;
  if (e < NE) {
    int r = edge_index[e * 2 + col];
    int pos = atomicAdd(&CUR[r], 1);
    IDX[pos] = e;
  }
}

// ---------------------------------------------------------------------------
// Fused edge kernel — processes edges in sender-sorted order (SIDX) for
// UPH/DOWNH L1/L2 locality. 64 edges/block, 256 threads (4 waves).
// Layers ping-pong HA<->HB; epilogue pipelined with dual accq buffers
// (next quarter's qgemm queued before each barrier). Index math identical
// to the round-4 verified kernel, plus SIDX indirection.
// ---------------------------------------------------------------------------
__device__ __forceinline__ void mlp_layer_256(
    const _Float16* In, _Float16* Out, const _Float16* __restrict__ Wz,
    int m, int g, int wv) {
  f32x4 acc[4][4];
  f32x4 zero4 = {0.f, 0.f, 0.f, 0.f};
#pragma unroll
  for (int rt = 0; rt < 4; ++rt)
#pragma unroll
    for (int ct = 0; ct < 4; ++ct) acc[rt][ct] = zero4;

#pragma unroll
  for (int kb = 0; kb < 8; ++kb) {
    f16x8 a[4], b[4];
#pragma unroll
    for (int rt = 0; rt < 4; ++rt) {
      int row = rt * 16 + m;
      a[rt] = *(const f16x8*)&In[row * 256 + (((kb * 2 + (g >> 1)) ^ m) << 4) + (g & 1) * 8];
    }
#pragma unroll
    for (int ct = 0; ct < 4; ++ct)
      b[ct] = *(const f16x8*)&Wz[((size_t)(kb * 256 + wv * 64 + ct * 16 + m) << 5) + g * 8];
#pragma unroll
    for (int rt = 0; rt < 4; ++rt)
#pragma unroll
      for (int ct = 0; ct < 4; ++ct)
        acc[rt][ct] = __builtin_amdgcn_mfma_f32_16x16x32_f16(a[rt], b[ct], acc[rt][ct], 0, 0, 0);
  }
#pragma unroll
  for (int rt = 0; rt < 4; ++rt)
#pragma unroll
    for (int q = 0; q < 4; ++q) {
      int row = rt * 16 + g * 4 + q;
      f16x4 pk;
#pragma unroll
      for (int ct = 0; ct < 4; ++ct) pk[ct] = (_Float16)silu_f(acc[rt][ct][q]);
      int blk = (wv * 4 + (m >> 2)) ^ (row & 15);
      *(f16x4*)&Out[row * 256 + (blk << 4) + (m & 3) * 4] = pk;
    }
}

__global__ __launch_bounds__(256, 2) void edge_mlp(
    const float* __restrict__ edge_attrs,
    const float* __restrict__ edge_feats,
    const int* __restrict__ edge_index,
    const int* __restrict__ SIDX,
    const _Float16* __restrict__ DOWNH,
    const _Float16* __restrict__ UPH,
    const _Float16* __restrict__ W0h, const _Float16* __restrict__ W1h,
    const _Float16* __restrict__ W2h, const _Float16* __restrict__ W3h,
    const _Float16* __restrict__ WL0h, const _Float16* __restrict__ WL1h,
    _Float16* __restrict__ MIDs) {
  __shared__ _Float16 HA[64 * 256];
  __shared__ _Float16 HB[64 * 256];

  const int tid = threadIdx.x;
  const int lane = tid & 63;
  const int wv = tid >> 6;
  const int m = lane & 15;
  const int g = lane >> 4;
  const int e0 = blockIdx.x * 64;
  const int nw = wv * 64;

  int el_r[4], snd_r[4], rcv_r[4];
#pragma unroll
  for (int rt = 0; rt < 4; ++rt) {
    el_r[rt] = SIDX[e0 + rt * 16 + m];
    int2 sr = *(const int2*)&edge_index[(size_t)el_r[rt] * 2];
    snd_r[rt] = sr.x;
    rcv_r[rt] = sr.y;
  }

  f32x4 zero4 = {0.f, 0.f, 0.f, 0.f};
  f16x8 zf = {0, 0, 0, 0, 0, 0, 0, 0};

  // ---------------- layer 0: aug(136, padded 160) -> h1 (HA)
  {
    f32x4 acc[4][4];
#pragma unroll
    for (int rt = 0; rt < 4; ++rt)
#pragma unroll
      for (int ct = 0; ct < 4; ++ct) acc[rt][ct] = zero4;

#pragma unroll
    for (int kb = 0; kb < 5; ++kb) {
      const int k0 = kb * 32 + g * 8;
      f16x8 a[4], b[4];
#pragma unroll
      for (int rt = 0; rt < 4; ++rt) {
        if (k0 == 0) {
          const float* ef = &edge_feats[(size_t)el_r[rt] * 8];
          float4 f0 = *(const float4*)ef;
          float4 f1 = *(const float4*)(ef + 4);
          f16x8 av;
          av[0] = (_Float16)f0.x; av[1] = (_Float16)f0.y;
          av[2] = (_Float16)f0.z; av[3] = (_Float16)f0.w;
          av[4] = (_Float16)f1.x; av[5] = (_Float16)f1.y;
          av[6] = (_Float16)f1.z; av[7] = (_Float16)f1.w;
          a[rt] = av;
        } else if (k0 < 72) {
          a[rt] = *(const f16x8*)&DOWNH[(size_t)snd_r[rt] * 64 + (k0 - 8)];
        } else if (k0 < 136) {
          a[rt] = *(const f16x8*)&DOWNH[(size_t)rcv_r[rt] * 64 + (k0 - 72)];
        } else {
          a[rt] = zf;
        }
      }
#pragma unroll
      for (int ct = 0; ct < 4; ++ct)
        b[ct] = *(const f16x8*)&W0h[((size_t)(kb * 256 + nw + ct * 16 + m) << 5) + g * 8];
#pragma unroll
      for (int rt = 0; rt < 4; ++rt)
#pragma unroll
        for (int ct = 0; ct < 4; ++ct)
          acc[rt][ct] = __builtin_amdgcn_mfma_f32_16x16x32_f16(a[rt], b[ct], acc[rt][ct], 0, 0, 0);
    }
#pragma unroll
    for (int rt = 0; rt < 4; ++rt)
#pragma unroll
      for (int q = 0; q < 4; ++q) {
        int row = rt * 16 + g * 4 + q;
        f16x4 pk;
#pragma unroll
        for (int ct = 0; ct < 4; ++ct) pk[ct] = (_Float16)silu_f(acc[rt][ct][q]);
        int blk = (wv * 4 + (m >> 2)) ^ (row & 15);
        *(f16x4*)&HA[row * 256 + (blk << 4) + (m & 3) * 4] = pk;
      }
  }
  __syncthreads();

  mlp_layer_256(HA, HB, W1h, m, g, wv);   // layer 1: h1 -> h2
  __syncthreads();
  mlp_layer_256(HB, HA, W2h, m, g, wv);   // layer 2: h2 -> h3 (HA stays live)
  __syncthreads();

  // ================= epilogue =================
  _Float16* SW = HB;             // 64 x 128 fp16, tpw quarter
  _Float16* SP = HB + 64 * 128;  // 64 x 128 fp16, TP'd A-matrix

  const int e_loc = lane;
  const int ers = (e_loc ^ (e_loc >> 3)) & 7;
  const int elc = SIDX[e0 + e_loc];
  const int snd_e = edge_index[(size_t)elc * 2];
  const _Float16* uprow = &UPH[(size_t)snd_e * 512];

  // quarter GEMM into caller-provided acc buffer
  auto qgemm = [&](int qbase, f32x4 (&accq)[4][2]) {
#pragma unroll
    for (int rt = 0; rt < 4; ++rt)
#pragma unroll
      for (int ct = 0; ct < 2; ++ct) accq[rt][ct] = zero4;
#pragma unroll
    for (int kb = 0; kb < 8; ++kb) {
      f16x8 a[4], b[2];
#pragma unroll
      for (int rt = 0; rt < 4; ++rt) {
        int row = rt * 16 + m;
        a[rt] = *(const f16x8*)&HA[row * 256 + (((kb * 2 + (g >> 1)) ^ m) << 4) + (g & 1) * 8];
      }
#pragma unroll
      for (int ct = 0; ct < 2; ++ct)
        b[ct] = *(const f16x8*)&W3h[((size_t)(kb * 512 + qbase + wv * 32 + ct * 16 + m) << 5) + g * 8];
#pragma unroll
      for (int rt = 0; rt < 4; ++rt)
#pragma unroll
        for (int ct = 0; ct < 2; ++ct)
          accq[rt][ct] = __builtin_amdgcn_mfma_f32_16x16x32_f16(a[rt], b[ct], accq[rt][ct], 0, 0, 0);
    }
  };

  auto sw_write = [&](const f32x4 (&accq)[4][2]) {
#pragma unroll
    for (int rt = 0; rt < 4; ++rt)
#pragma unroll
      for (int r4 = 0; r4 < 4; ++r4) {
        int row = rt * 16 + g * 4 + r4;
        int rs = (row ^ (row >> 3)) & 7;
        f16x2 pk;
        pk[0] = (_Float16)accq[rt][0][r4];
        pk[1] = (_Float16)accq[rt][1][r4];
        int blk = ((wv * 2 + (m >> 3)) ^ rs) & 7;
        *(f16x2*)&SW[row * 128 + (blk << 4) + (m & 7) * 2] = pk;
      }
  };

  auto fold = [&](const _Float16* __restrict__ WLh, int qpart, f32x4 (&P)[4][2]) {
#pragma unroll
    for (int rt = 0; rt < 4; ++rt)
#pragma unroll
      for (int ct = 0; ct < 2; ++ct) P[rt][ct] = zero4;
#pragma unroll
    for (int kb = 0; kb < 4; ++kb) {
      f16x8 a[4], b[2];
#pragma unroll
      for (int rt = 0; rt < 4; ++rt) {
        int row = rt * 16 + m;
        int rs = (row ^ (row >> 3)) & 7;
        a[rt] = *(const f16x8*)&SP[row * 128 + ((((kb * 2 + (g >> 1)) ^ rs) & 7) << 4) + (g & 1) * 8];
      }
#pragma unroll
      for (int ct = 0; ct < 2; ++ct)
        b[ct] = *(const f16x8*)&WLh[((size_t)((qpart * 4 + kb) * 128 + wv * 32 + ct * 16 + m) << 5) + g * 8];
#pragma unroll
      for (int rt = 0; rt < 4; ++rt)
#pragma unroll
        for (int ct = 0; ct < 2; ++ct)
          P[rt][ct] = __builtin_amdgcn_mfma_f32_16x16x32_f16(a[rt], b[ct], P[rt][ct], 0, 0, 0);
    }
  };

  auto tp_xs = [&]() {
#pragma unroll
    for (int cch = 0; cch < 4; ++cch) {
      int ib = nw / 2 + cch * 8;
      int blk = ((ib >> 4) ^ ers) & 7;
      int off = e_loc * 128 + (blk << 4) + (ib & 15);
      f16x8 swv = *(const f16x8*)&SW[off];
      f16x8 upv = *(const f16x8*)&uprow[ib];
      f16x8 pr = swv * upv;
      *(f16x8*)&SP[off] = pr;
    }
  };

  _Float16 xvb[96];
  auto load_xv = [&]() {
#pragma unroll
    for (int u = 0; u < 12; ++u) {
      f16x8 t = *(const f16x8*)&uprow[128 + wv * 96 + u * 8];
#pragma unroll
      for (int z = 0; z < 8; ++z) xvb[u * 8 + z] = t[z];
    }
  };

  auto tp_w4 = [&]() {
    float4 ea = *(const float4*)&edge_attrs[(size_t)elc * 4];
#pragma unroll
    for (int cch = 0; cch < 4; ++cch) {
      int ib = nw / 2 + cch * 8;
      int blk = ((ib >> 4) ^ ers) & 7;
      int off = e_loc * 128 + (blk << 4) + (ib & 15);
      f16x8 swv = *(const f16x8*)&SW[off];
      f16x8 outv;
#pragma unroll
      for (int z = 0; z < 8; ++z) {
        int k = cch * 8 + z;
        float d = (float)xvb[k * 3] * ea.y + (float)xvb[k * 3 + 1] * ea.z +
                  (float)xvb[k * 3 + 2] * ea.w;
        outv[z] = (_Float16)((float)swv[z] * d);
      }
      *(f16x8*)&SP[off] = outv;
    }
  };

  auto tp_w3 = [&](int c) {
#pragma unroll
    for (int cch = 0; cch < 4; ++cch) {
      int ib = nw / 2 + cch * 8;
      int blk = ((ib >> 4) ^ ers) & 7;
      int off = e_loc * 128 + (blk << 4) + (ib & 15);
      f16x8 swv = *(const f16x8*)&SW[off];
      f16x8 outv;
#pragma unroll
      for (int z = 0; z < 8; ++z) {
        int k = cch * 8 + z;
        outv[z] = swv[z] * xvb[k * 3 + c];
      }
      *(f16x8*)&SP[off] = outv;
    }
  };

  f32x4 accqA[4][2], accqB[4][2];
  f32x4 P1[4][2], P4[4][2], P2[4][2], P3[4][2];

  // q1 (w1): A1 = w1 (x) xs ; P1 = A1 @ WL0a. Queue q4 gemm before barrier.
  qgemm(0, accqA);
  sw_write(accqA);
  tp_xs();
  qgemm(384, accqB);          // w4, independent — fills the barrier wait
  __syncthreads();            // B1: SP(A1) complete
  fold(WL0h, 0, P1);
  sw_write(accqB);            // SW <- w4 (SW(w1) readers all pre-B1)
  load_xv();
  __syncthreads();            // B2: all folds done reading SP(A1)
  tp_w4();
  qgemm(128, accqA);          // w2 queued
  __syncthreads();            // B3: SP(A4) complete
  fold(WL0h, 1, P4);
  sw_write(accqA);            // SW <- w2 (tp_w4 reads all pre-B3)

  // scalar part: MIDs[:, j] = y0*P1 + P4/sqrt(3)
#pragma unroll
  for (int rt = 0; rt < 4; ++rt)
#pragma unroll
    for (int r4 = 0; r4 < 4; ++r4) {
      int row = rt * 16 + g * 4 + r4;
      int elw = SIDX[e0 + row];
      float4 ea = *(const float4*)&edge_attrs[(size_t)elw * 4];
      f16x2 pk;
      pk[0] = (_Float16)(ea.x * P1[rt][0][r4] + INV_SQRT3F * P4[rt][0][r4]);
      pk[1] = (_Float16)(ea.x * P1[rt][1][r4] + INV_SQRT3F * P4[rt][1][r4]);
      *(f16x2*)&MIDs[(size_t)elw * 512 + wv * 32 + m * 2] = pk;
    }
  __syncthreads();            // B4: folds done reading SP(A4)
  tp_xs();                    // SP <- A2 (reads SW(w2), own wave, pre-B4)
  qgemm(256, accqB);          // w3 queued
  __syncthreads();            // B5: SP(A2) complete
  fold(WL1h, 0, P2);
  sw_write(accqB);            // SW <- w3 (tp_xs reads all pre-B5)
  __syncthreads();            // B6: folds done reading SP(A2)

#pragma unroll
  for (int c = 0; c < 3; ++c) {
    tp_w3(c);                 // SP <- A3c (reads SW(w3), own wave)
    __syncthreads();          // SP complete
    fold(WL1h, 1, P3);
    // plane c: MIDs[:, 128 + c*128 + j] = yv[c]*P2 + y0*P3
#pragma unroll
    for (int rt = 0; rt < 4; ++rt)
#pragma unroll
      for (int r4 = 0; r4 < 4; ++r4) {
        int row = rt * 16 + g * 4 + r4;
        int elw = SIDX[e0 + row];
        float4 ea = *(const float4*)&edge_attrs[(size_t)elw * 4];
        float yvc = (c == 0) ? ea.y : (c == 1) ? ea.z : ea.w;
        f16x2 pk;
        pk[0] = (_Float16)(yvc * P2[rt][0][r4] + ea.x * P3[rt][0][r4]);
        pk[1] = (_Float16)(yvc * P2[rt][1][r4] + ea.x * P3[rt][1][r4]);
        *(f16x2*)&MIDs[(size_t)elw * 512 + 128 + c * 128 + wv * 32 + m * 2] = pk;
      }
    if (c < 2) __syncthreads();  // folds done reading SP before next tp_w3
  }
}

// ---------------------------------------------------------------------------
// Gather: one block per node; LDS-staged edge ids + 4-way unroll; output row
// staged in LDS and stored coalesced (float2/lane) instead of 4-strided.
// ---------------------------------------------------------------------------
__global__ __launch_bounds__(256) void gather_msg(
    const _Float16* __restrict__ MIDs, const int* __restrict__ OFF,
    const int* __restrict__ EIDX, float* __restrict__ out) {
  __shared__ int eb[256];
  __shared__ float os[512];
  const int n = blockIdx.x;
  const int t = threadIdx.x;
  const int beg = OFF[n], end = OFF[n + 1];
  float a0 = 0.f, a1 = 0.f;
  for (int base = beg; base < end; base += 256) {
    int cnt = min(256, end - base);
    __syncthreads();
    if (t < cnt) eb[t] = EIDX[base + t];
    __syncthreads();
    int k = 0;
    for (; k + 4 <= cnt; k += 4) {
      int e0_ = eb[k], e1_ = eb[k + 1], e2_ = eb[k + 2], e3_ = eb[k + 3];
      f16x2 v0 = *(const f16x2*)&MIDs[(size_t)e0_ * 512 + t * 2];
      f16x2 v1 = *(const f16x2*)&MIDs[(size_t)e1_ * 512 + t * 2];
      f16x2 v2 = *(const f16x2*)&MIDs[(size_t)e2_ * 512 + t * 2];
      f16x2 v3 = *(const f16x2*)&MIDs[(size_t)e3_ * 512 + t * 2];
      a0 += (float)v0[0] + (float)v1[0] + (float)v2[0] + (float)v3[0];
      a1 += (float)v0[1] + (float)v1[1] + (float)v2[1] + (float)v3[1];
    }
    for (; k < cnt; ++k) {
      f16x2 v = *(const f16x2*)&MIDs[(size_t)eb[k] * 512 + t * 2];
      a0 += (float)v[0];
      a1 += (float)v[1];
    }
  }
#pragma unroll
  for (int u = 0; u < 2; ++u) {
    int x = t * 2 + u;
    float a = u ? a1 : a0;
    int dst;
    if (x < 128) {
      dst = x * 4;
    } else {
      int xm = x - 128;
      int c = xm >> 7, j = xm & 127;
      dst = j * 4 + 1 + c;
    }
    os[dst] = a;
  }
  __syncthreads();
  *(float2*)&out[(size_t)n * 512 + t * 2] = *(const float2*)&os[t * 2];
}

// ---------------------------------------------------------------------------
extern "C" void kernel_launch(void* const* d_in, const int* in_sizes, int n_in,
                              void* d_out, int out_size, void* d_ws, size_t ws_size,
                              hipStream_t stream) {
  const float* node_feats = (const float*)d_in[1];
  const float* edge_attrs = (const float*)d_in[2];
  const float* edge_feats = (const float*)d_in[3];
  const int*   edge_index = (const int*)d_in[4];
  const float* W_up0   = (const float*)d_in[5];
  const float* W_up1   = (const float*)d_in[6];
  const float* W_down  = (const float*)d_in[7];
  const float* Wm0     = (const float*)d_in[8];
  const float* Wm1     = (const float*)d_in[9];
  const float* Wm2     = (const float*)d_in[10];
  const float* Wm3     = (const float*)d_in[11];
  const float* W_lin0  = (const float*)d_in[12];
  const float* W_lin1  = (const float*)d_in[13];
  const float* W_skip0 = (const float*)d_in[14];
  const float* W_skip1 = (const float*)d_in[15];
  float* out = (float*)d_out;

  char* ws = (char*)d_ws;
  size_t off = 0;
  auto alloc = [&](size_t bytes) {
    void* p = ws + off;
    off = (off + bytes + 255) & ~(size_t)255;
    return p;
  };
  _Float16* UPH   = (_Float16*)alloc((size_t)NN * 512 * 2);
  _Float16* DOWNH = (_Float16*)alloc((size_t)NN * 64 * 2);
  _Float16* W0h   = (_Float16*)alloc(160 * 256 * 2);
  _Float16* W1h   = (_Float16*)alloc(256 * 256 * 2);
  _Float16* W2h   = (_Float16*)alloc(256 * 256 * 2);
  _Float16* W3h   = (_Float16*)alloc(256 * 512 * 2);
  _Float16* WL0h  = (_Float16*)alloc(256 * 128 * 2);
  _Float16* WL1h  = (_Float16*)alloc(256 * 128 * 2);
  int*      CNT   = (int*)alloc((size_t)NN * 4);
  int*      OFF   = (int*)alloc((size_t)(NN + 1) * 4);
  int*      CUR   = (int*)alloc((size_t)NN * 4);
  int*      EIDX  = (int*)alloc((size_t)NE * 4);
  int*      CNT2  = (int*)alloc((size_t)NN * 4);
  int*      OFF2  = (int*)alloc((size_t)(NN + 1) * 4);
  int*      CUR2  = (int*)alloc((size_t)NN * 4);
  int*      SIDX  = (int*)alloc((size_t)NE * 4);
  _Float16* MIDs  = (_Float16*)alloc((size_t)NE * 512 * 2);

  hipMemsetAsync(CNT, 0, (size_t)NN * 4, stream);
  hipMemsetAsync(CNT2, 0, (size_t)NN * 4, stream);

  // scales folded into fp16 weights: 1/sqrt(136) layer0, 1/16 layers 1..3,
  // 1/256 for W_lin (includes sqrt(2C) and AVG_NEIGH)
  wconv<<<160, 256, 0, stream>>>(Wm0, W0h, 136, 160, 256, 1.0f / sqrtf(136.0f), 64);
  wconv<<<256, 256, 0, stream>>>(Wm1, W1h, 256, 256, 256, 0.0625f, 64);
  wconv<<<256, 256, 0, stream>>>(Wm2, W2h, 256, 256, 256, 0.0625f, 64);
  wconv<<<512, 256, 0, stream>>>(Wm3, W3h, 256, 256, 512, 0.0625f, 32);
  wconv<<<128, 256, 0, stream>>>(W_lin0, WL0h, 256, 256, 128, 1.0f / 256.0f, 32);
  wconv<<<128, 256, 0, stream>>>(W_lin1, WL1h, 256, 256, 128, 1.0f / 256.0f, 32);

  node_pre_s<<<625, 256, 0, stream>>>(node_feats, W_up0, W_skip0, W_down,
                                      UPH, DOWNH, out + (size_t)NN * 512);
  node_pre_v<<<625, 256, 0, stream>>>(node_feats, W_up1, W_skip1,
                                      UPH, out + (size_t)NN * 512);

  // receiver CSR (gather) + sender CSR (edge processing order)
  k_count<<<625, 256, 0, stream>>>(edge_index, CNT, 1);
  k_count<<<625, 256, 0, stream>>>(edge_index, CNT2, 0);
  k_scan<<<1, 1024, 0, stream>>>(CNT, OFF, CUR);
  k_scan<<<1, 1024, 0, stream>>>(CNT2, OFF2, CUR2);
  k_fill<<<625, 256, 0, stream>>>(edge_index, CUR, EIDX, 1);
  k_fill<<<625, 256, 0, stream>>>(edge_index, CUR2, SIDX, 0);

  edge_mlp<<<2500, 256, 0, stream>>>(edge_attrs, edge_feats, edge_index, SIDX,
                                     DOWNH, UPH, W0h, W1h, W2h, W3h, WL0h, WL1h,
                                     MIDs);
  gather_msg<<<NN, 256, 0, stream>>>(MIDs, OFF, EIDX, out);
}